// Round 1
// baseline (2014.407 us; speedup 1.0000x reference)
//
#include <hip/hip_runtime.h>
#include <math.h>

// ---- problem constants ----
static constexpr int B_  = 16;
static constexpr int N_  = 32;
static constexpr int E_  = 256;
static constexpr int D_  = 256;
static constexpr int H_  = 8;
static constexpr int HW_ = 784;
static constexpr int L_  = 4;
static constexpr int DH_ = 32;
static constexpr int FF_ = 1024;
static constexpr int BN_ = 512;
static constexpr int BE_ = 4096;
static constexpr int NE_ = 288;   // N+E
#define SCALE_ 0.17677669529663687f

__device__ __forceinline__ float gelu_f(float x) {
    return 0.5f * x * (1.0f + erff(x * 0.7071067811865476f));
}

// ---------------- elementwise / LN kernels ----------------

__global__ void concat_kernel(const float* __restrict__ nodes, const float* __restrict__ edges,
                              float* __restrict__ ne) {
    int tid = blockIdx.x * 256 + threadIdx.x;   // B*NE*D
    int d = tid & 255;
    int row = tid >> 8;
    int b = row / NE_, pos = row % NE_;
    float v = (pos < N_) ? nodes[(size_t)(b * N_ + pos) * D_ + d]
                         : edges[(size_t)(b * E_ + (pos - N_)) * D_ + d];
    ne[tid] = v;
}

__global__ __launch_bounds__(256) void ln_kernel(const float* __restrict__ x, float* __restrict__ y,
                                                 const float* __restrict__ g, const float* __restrict__ bta) {
    const int row = blockIdx.x;
    const int d = threadIdx.x;
    float v = x[(size_t)row * D_ + d];
    float s = v, s2 = v * v;
    #pragma unroll
    for (int o = 32; o >= 1; o >>= 1) { s += __shfl_down(s, o); s2 += __shfl_down(s2, o); }
    __shared__ float sh1[4], sh2[4];
    int lane = d & 63, w = d >> 6;
    if (lane == 0) { sh1[w] = s; sh2[w] = s2; }
    __syncthreads();
    if (d == 0) {
        float a = sh1[0] + sh1[1] + sh1[2] + sh1[3];
        float c = sh2[0] + sh2[1] + sh2[2] + sh2[3];
        sh1[0] = a; sh2[0] = c;
    }
    __syncthreads();
    float mean = sh1[0] * (1.0f / D_);
    float var  = sh2[0] * (1.0f / D_) - mean * mean;
    float rstd = rsqrtf(var + 1e-5f);
    y[(size_t)row * D_ + d] = (v - mean) * rstd * g[d] + bta[d];
}

// ---------------- GEMM: C[M,N] = epi(A[M,K] @ B[K,N] + bias) ----------------
// MODE 0: C = acc+bias ; MODE 1: C = gelu(acc+bias) ; MODE 2: C = res + ls*(acc+bias)
template<int MODE>
__global__ __launch_bounds__(256) void gemm_kernel(
    const float* __restrict__ A, int lda,
    const float* __restrict__ Bm, int ldb,
    const float* __restrict__ bias,
    const float* __restrict__ res,
    const float* __restrict__ ls,
    float* __restrict__ C, int ldc,
    int M, int K)
{
    __shared__ float As[16][64];
    __shared__ float Bs[16][64];
    const int n0 = blockIdx.x * 64;
    const int m0 = blockIdx.y * 64;
    const int t = threadIdx.x;
    const int tx = t & 15, ty = t >> 4;
    const int ai = t >> 2, aj = (t & 3) << 2;
    const int bj = t >> 4, bi = (t & 15) << 2;
    float acc[4][4] = {};
    for (int k0 = 0; k0 < K; k0 += 16) {
        float4 a4 = *(const float4*)(A + (size_t)(m0 + ai) * lda + k0 + aj);
        float4 b4 = *(const float4*)(Bm + (size_t)(k0 + bj) * ldb + n0 + bi);
        __syncthreads();
        As[aj + 0][ai] = a4.x; As[aj + 1][ai] = a4.y; As[aj + 2][ai] = a4.z; As[aj + 3][ai] = a4.w;
        *(float4*)&Bs[bj][bi] = b4;
        __syncthreads();
        #pragma unroll
        for (int kk = 0; kk < 16; ++kk) {
            float4 av = *(const float4*)&As[kk][ty * 4];
            float4 bv = *(const float4*)&Bs[kk][tx * 4];
            acc[0][0] += av.x * bv.x; acc[0][1] += av.x * bv.y; acc[0][2] += av.x * bv.z; acc[0][3] += av.x * bv.w;
            acc[1][0] += av.y * bv.x; acc[1][1] += av.y * bv.y; acc[1][2] += av.y * bv.z; acc[1][3] += av.y * bv.w;
            acc[2][0] += av.z * bv.x; acc[2][1] += av.z * bv.y; acc[2][2] += av.z * bv.z; acc[2][3] += av.z * bv.w;
            acc[3][0] += av.w * bv.x; acc[3][1] += av.w * bv.y; acc[3][2] += av.w * bv.z; acc[3][3] += av.w * bv.w;
        }
    }
    #pragma unroll
    for (int r = 0; r < 4; ++r) {
        int m = m0 + ty * 4 + r;
        #pragma unroll
        for (int c = 0; c < 4; ++c) {
            int n = n0 + tx * 4 + c;
            float v = acc[r][c] + bias[n];
            if (MODE == 1) v = gelu_f(v);
            if (MODE == 2) v = res[(size_t)m * ldc + n] + ls[n] * v;
            C[(size_t)m * ldc + n] = v;
        }
    }
}

// ---------------- flash attention ----------------
// grid (9, H, B), block 256. 32 q-rows/block, 8 lanes per row, KV chunks of 64.
__global__ __launch_bounds__(256) void attn_kernel(
    const float* __restrict__ q, const float* __restrict__ k,
    const float* __restrict__ v, const float* __restrict__ mask,
    float* __restrict__ ctx)
{
    const int qt = blockIdx.x, h = blockIdx.y, b = blockIdx.z;
    const int q0 = qt * 32;
    const int t = threadIdx.x;
    const int r = t >> 3, j = t & 7;
    __shared__ float Ks[64][36];
    __shared__ float Vs[64][36];
    float qreg[32];
    {
        const float* qrow = q + (size_t)(b * NE_ + q0 + r) * D_ + h * DH_;
        #pragma unroll
        for (int i = 0; i < 8; ++i) {
            float4 t4 = *(const float4*)(qrow + i * 4);
            qreg[i * 4 + 0] = t4.x; qreg[i * 4 + 1] = t4.y;
            qreg[i * 4 + 2] = t4.z; qreg[i * 4 + 3] = t4.w;
        }
    }
    float m_i = -INFINITY, l_i = 0.f;
    float accv[32];
    #pragma unroll
    for (int i = 0; i < 32; ++i) accv[i] = 0.f;
    const float* mrow = mask + ((size_t)(b * H_ + h) * NE_ + q0 + r) * HW_;

    for (int c0 = 0; c0 < HW_; c0 += 64) {
        const int nvalid = (HW_ - c0 < 64) ? (HW_ - c0) : 64;
        __syncthreads();
        {
            int rr = t >> 2, cc = (t & 3) * 8;
            if (rr < nvalid) {
                const float* krow = k + (size_t)(b * HW_ + c0 + rr) * D_ + h * DH_ + cc;
                const float* vrow = v + (size_t)(b * HW_ + c0 + rr) * D_ + h * DH_ + cc;
                float4 k4a = *(const float4*)(krow);
                float4 k4b = *(const float4*)(krow + 4);
                float4 v4a = *(const float4*)(vrow);
                float4 v4b = *(const float4*)(vrow + 4);
                *(float4*)&Ks[rr][cc] = k4a; *(float4*)&Ks[rr][cc + 4] = k4b;
                *(float4*)&Vs[rr][cc] = v4a; *(float4*)&Vs[rr][cc + 4] = v4b;
            }
        }
        __syncthreads();
        float sc[8];
        #pragma unroll
        for (int s = 0; s < 8; ++s) {
            int kk = j + s * 8;
            float a = 0.f;
            #pragma unroll
            for (int i = 0; i < 8; ++i) {
                float4 k4 = *(const float4*)&Ks[kk][i * 4];
                a += qreg[i * 4] * k4.x + qreg[i * 4 + 1] * k4.y + qreg[i * 4 + 2] * k4.z + qreg[i * 4 + 3] * k4.w;
            }
            int kabs = c0 + kk;
            sc[s] = (kabs < HW_) ? (a * SCALE_ + mrow[kabs]) : -INFINITY;
        }
        float mloc = sc[0];
        #pragma unroll
        for (int s = 1; s < 8; ++s) mloc = fmaxf(mloc, sc[s]);
        #pragma unroll
        for (int o = 1; o < 8; o <<= 1) mloc = fmaxf(mloc, __shfl_xor(mloc, o));
        float m_new = fmaxf(m_i, mloc);
        float scl = expf(m_i - m_new);    // first chunk: exp(-inf)=0
        float p[8]; float lloc = 0.f;
        #pragma unroll
        for (int s = 0; s < 8; ++s) { p[s] = expf(sc[s] - m_new); lloc += p[s]; }
        #pragma unroll
        for (int o = 1; o < 8; o <<= 1) lloc += __shfl_xor(lloc, o);
        l_i = l_i * scl + lloc;
        m_i = m_new;
        #pragma unroll
        for (int i = 0; i < 32; ++i) accv[i] *= scl;
        #pragma unroll
        for (int s = 0; s < 8; ++s) {
            int kk = j + s * 8;
            float pv = p[s];
            #pragma unroll
            for (int i = 0; i < 8; ++i) {
                float4 v4 = *(const float4*)&Vs[kk][i * 4];
                accv[i * 4 + 0] += pv * v4.x; accv[i * 4 + 1] += pv * v4.y;
                accv[i * 4 + 2] += pv * v4.z; accv[i * 4 + 3] += pv * v4.w;
            }
        }
    }
    // reduce partial ctx across the 8 lanes of this row
    #pragma unroll
    for (int i = 0; i < 32; ++i) {
        float a = accv[i];
        a += __shfl_xor(a, 1); a += __shfl_xor(a, 2); a += __shfl_xor(a, 4);
        accv[i] = a;
    }
    float inv_l = 1.0f / l_i;
    float* crow = ctx + (size_t)(b * NE_ + q0 + r) * D_ + h * DH_ + j * 4;
    float4 o4 = make_float4(accv[j * 4] * inv_l, accv[j * 4 + 1] * inv_l,
                            accv[j * 4 + 2] * inv_l, accv[j * 4 + 3] * inv_l);
    *(float4*)crow = o4;
}

// ---------------- GAT kernels ----------------

__global__ void addenc_kernel(const float* __restrict__ ln, const float* __restrict__ node_enc,
                              const float* __restrict__ edge_enc,
                              float* __restrict__ nodes_f, float* __restrict__ edges_f) {
    int tid = blockIdx.x * 256 + threadIdx.x;   // B*NE*D
    int d = tid & 255;
    int row = tid >> 8;
    int b = row / NE_, pos = row % NE_;
    float v = ln[tid];
    if (pos < N_) {
        int rn = b * N_ + pos;
        nodes_f[(size_t)rn * D_ + d] = v + node_enc[(size_t)rn * D_ + d];
    } else {
        int re = b * E_ + (pos - N_);
        edges_f[(size_t)re * D_ + d] = v + edge_enc[(size_t)re * D_ + d];
    }
}

// hid holds ep on entry; out: hid = gelu(gn1[idx0]+gn2[idx0]+ep), pres[e][h]
__global__ __launch_bounds__(256) void hidden_kernel(
    const float* __restrict__ gn1, const float* __restrict__ gn2,
    float* __restrict__ hid, const int* __restrict__ idx0,
    const float* __restrict__ attn_p_l, float* __restrict__ pres) {
    int e = blockIdx.x;
    int d = threadIdx.x;
    int n = idx0[e];
    float x = hid[(size_t)e * D_ + d] + gn1[(size_t)n * D_ + d] + gn2[(size_t)n * D_ + d];
    float hv = gelu_f(x);
    hid[(size_t)e * D_ + d] = hv;
    float pr = hv * attn_p_l[d];
    #pragma unroll
    for (int o = 1; o < 32; o <<= 1) pr += __shfl_xor(pr, o);
    if ((d & 31) == 0) pres[e * H_ + (d >> 5)] = pr;
}

__global__ void segsoft_kernel(const float* __restrict__ pres, const int* __restrict__ csr_off,
                               const int* __restrict__ csr_perm,
                               float* __restrict__ mseg, float* __restrict__ denom) {
    int tid = blockIdx.x * 256 + threadIdx.x;   // BN*H
    int n = tid >> 3, h = tid & 7;
    int s = csr_off[n], e2 = csr_off[n + 1];
    float mx = -INFINITY;
    for (int i = s; i < e2; ++i) mx = fmaxf(mx, pres[csr_perm[i] * H_ + h]);
    float sum = 0.f;
    for (int i = s; i < e2; ++i) sum += expf(pres[csr_perm[i] * H_ + h] - mx);
    mseg[tid] = mx;
    denom[tid] = sum;
}

__global__ void alpha_kernel(const float* __restrict__ pres, const int* __restrict__ idx0,
                             const float* __restrict__ mseg, const float* __restrict__ denom,
                             float* __restrict__ alpha) {
    int tid = blockIdx.x * 256 + threadIdx.x;   // BE*H
    int e = tid >> 3, h = tid & 7;
    int n = idx0[e];
    alpha[tid] = expf(pres[tid] - mseg[n * H_ + h]) / denom[n * H_ + h];
}

__global__ void vin_kernel(const float* __restrict__ nodes_f, const float* __restrict__ new_edges,
                           const int* __restrict__ idx1, float* __restrict__ vin) {
    int tid = blockIdx.x * 256 + threadIdx.x;   // BE*D
    int e = tid >> 8, d = tid & 255;
    vin[tid] = nodes_f[(size_t)idx1[e] * D_ + d] + new_edges[tid];
}

__global__ __launch_bounds__(256) void nodeagg_kernel(
    const float* __restrict__ vals, const float* __restrict__ alpha,
    const int* __restrict__ csr_off, const int* __restrict__ csr_perm,
    float* __restrict__ new_nodes) {
    int n = blockIdx.x;
    int d = threadIdx.x;
    int s = csr_off[n], e2 = csr_off[n + 1];
    int h = d >> 5;
    float acc = 0.f;
    for (int i = s; i < e2; ++i) {
        int e = csr_perm[i];
        acc += vals[(size_t)e * D_ + d] * alpha[e * H_ + h];
    }
    new_nodes[(size_t)n * D_ + d] = acc;
}

__global__ void gatres_kernel(float* __restrict__ ne, const float* __restrict__ new_nodes,
                              const float* __restrict__ new_edges, const float* __restrict__ ls2l) {
    int tid = blockIdx.x * 256 + threadIdx.x;   // B*NE*D
    int d = tid & 255;
    int row = tid >> 8;
    int b = row / NE_, pos = row % NE_;
    float g = (pos < N_) ? new_nodes[(size_t)(b * N_ + pos) * D_ + d]
                         : new_edges[(size_t)(b * E_ + (pos - N_)) * D_ + d];
    ne[tid] += ls2l[d] * g;
}

// ---------------- CSR build (deterministic) ----------------

__global__ void zero_counts(int* counts) {
    int t = blockIdx.x * 256 + threadIdx.x;
    if (t < BN_) counts[t] = 0;
}

__global__ void csr_count(const int* __restrict__ idx0, int* __restrict__ counts) {
    int e = blockIdx.x * 256 + threadIdx.x;
    if (e < BE_) atomicAdd(&counts[idx0[e]], 1);
}

__global__ __launch_bounds__(512) void csr_scan(const int* __restrict__ counts, int* __restrict__ csr_off) {
    __shared__ int buf[BN_];
    int t = threadIdx.x;
    int c = counts[t];
    buf[t] = c;
    __syncthreads();
    for (int o = 1; o < BN_; o <<= 1) {
        int add = (t >= o) ? buf[t - o] : 0;
        __syncthreads();
        buf[t] += add;
        __syncthreads();
    }
    csr_off[t] = buf[t] - c;
    if (t == BN_ - 1) csr_off[BN_] = buf[t];
}

__global__ __launch_bounds__(64) void csr_fill(const int* __restrict__ idx0,
                                               const int* __restrict__ csr_off,
                                               int* __restrict__ csr_perm) {
    int n = blockIdx.x;
    int lane = threadIdx.x;
    int w = csr_off[n];
    for (int c0 = 0; c0 < BE_; c0 += 64) {
        int e = c0 + lane;
        bool m = (idx0[e] == n);
        unsigned long long bal = __ballot(m);
        if (m) {
            int pre = __popcll(bal & ((1ull << lane) - 1ull));
            csr_perm[w + pre] = e;
        }
        w += __popcll(bal);
    }
}

// ---------------- host orchestration ----------------

static void launch_gemm(hipStream_t s, int mode,
                        const float* A, int lda, const float* Bm, int ldb,
                        const float* bias, const float* res, const float* ls,
                        float* C, int ldc, int M, int N, int K) {
    dim3 g(N / 64, M / 64);
    if (mode == 0)      gemm_kernel<0><<<g, 256, 0, s>>>(A, lda, Bm, ldb, bias, res, ls, C, ldc, M, K);
    else if (mode == 1) gemm_kernel<1><<<g, 256, 0, s>>>(A, lda, Bm, ldb, bias, res, ls, C, ldc, M, K);
    else                gemm_kernel<2><<<g, 256, 0, s>>>(A, lda, Bm, ldb, bias, res, ls, C, ldc, M, K);
}

extern "C" void kernel_launch(void* const* d_in, const int* in_sizes, int n_in,
                              void* d_out, int out_size, void* d_ws, size_t ws_size,
                              hipStream_t stream) {
    const float* nodes    = (const float*)d_in[0];
    const float* edges    = (const float*)d_in[1];
    const float* images   = (const float*)d_in[2];
    const float* mask     = (const float*)d_in[3];
    const float* node_enc = (const float*)d_in[4];
    const float* edge_enc = (const float*)d_in[5];
    const float* ln1_g = (const float*)d_in[6];
    const float* ln1_b = (const float*)d_in[7];
    const float* Wqkv  = (const float*)d_in[8];
    const float* bqkv  = (const float*)d_in[9];
    const float* Wo    = (const float*)d_in[10];
    const float* bo    = (const float*)d_in[11];
    const float* ls1   = (const float*)d_in[12];
    const float* ln2_g = (const float*)d_in[13];
    const float* ln2_b = (const float*)d_in[14];
    const float* Wn1   = (const float*)d_in[15];
    const float* bn1   = (const float*)d_in[16];
    const float* Wn2   = (const float*)d_in[17];
    const float* bn2   = (const float*)d_in[18];
    const float* We    = (const float*)d_in[19];
    const float* be    = (const float*)d_in[20];
    const float* attn_p= (const float*)d_in[21];
    const float* Weo   = (const float*)d_in[22];
    const float* beo   = (const float*)d_in[23];
    const float* Wno   = (const float*)d_in[24];
    const float* bno   = (const float*)d_in[25];
    const float* ls2   = (const float*)d_in[26];
    const float* ln3_g = (const float*)d_in[27];
    const float* ln3_b = (const float*)d_in[28];
    const float* W1    = (const float*)d_in[29];
    const float* b1    = (const float*)d_in[30];
    const float* W2    = (const float*)d_in[31];
    const float* b2    = (const float*)d_in[32];
    const float* ls3   = (const float*)d_in[33];
    const int*   edge_index = (const int*)d_in[34];
    const int* idx0 = edge_index;
    const int* idx1 = edge_index + BE_;

    float* ne = (float*)d_out;   // d_out doubles as the running `ne` buffer

    float* cur = (float*)d_ws;
    auto alloc = [&](size_t nfl) { float* p = cur; cur += nfl; return p; };
    float* lnbuf    = alloc((size_t)B_ * NE_ * D_);
    float* qb       = alloc((size_t)B_ * NE_ * D_);
    float* kb       = alloc((size_t)B_ * HW_ * D_);
    float* vb       = alloc((size_t)B_ * HW_ * D_);
    float* ffnh     = kb;   // alias: k/v dead by FFN time (needs 4.7M of the 6.4M floats)
    float* ctxb     = alloc((size_t)B_ * NE_ * D_);
    float* nodes_f  = alloc((size_t)BN_ * D_);
    float* edges_f  = alloc((size_t)BE_ * D_);
    float* gn1      = alloc((size_t)BN_ * D_);
    float* gn2      = alloc((size_t)BN_ * D_);
    float* hid      = alloc((size_t)BE_ * D_);
    float* pres     = alloc((size_t)BE_ * H_);
    float* mseg     = alloc((size_t)BN_ * H_);
    float* denom    = alloc((size_t)BN_ * H_);
    float* alphab   = alloc((size_t)BE_ * H_);
    float* new_edges= alloc((size_t)BE_ * D_);
    float* vin      = alloc((size_t)BE_ * D_);
    float* valsb    = alloc((size_t)BE_ * D_);
    float* new_nodes= alloc((size_t)BN_ * D_);
    int* counts   = (int*)cur; cur += BN_;
    int* csr_off  = (int*)cur; cur += BN_ + 4;
    int* csr_perm = (int*)cur; cur += BE_;

    // CSR build (once; deterministic ordering by edge id)
    zero_counts<<<2, 256, 0, stream>>>(counts);
    csr_count<<<BE_ / 256, 256, 0, stream>>>(idx0, counts);
    csr_scan<<<1, 512, 0, stream>>>(counts, csr_off);
    csr_fill<<<BN_, 64, 0, stream>>>(idx0, csr_off, csr_perm);

    concat_kernel<<<(B_ * NE_ * D_) / 256, 256, 0, stream>>>(nodes, edges, ne);

    for (int l = 0; l < L_; ++l) {
        const float* Wqkv_l = Wqkv + (size_t)l * D_ * 3 * D_;
        const float* bqkv_l = bqkv + (size_t)l * 3 * D_;
        const float* Wo_l = Wo + (size_t)l * D_ * D_;
        const float* Wn1_l = Wn1 + (size_t)l * D_ * D_;
        const float* Wn2_l = Wn2 + (size_t)l * D_ * D_;
        const float* We_l  = We  + (size_t)l * D_ * D_;
        const float* Weo_l = Weo + (size_t)l * D_ * D_;
        const float* Wno_l = Wno + (size_t)l * D_ * D_;
        const float* W1_l  = W1  + (size_t)l * D_ * FF_;
        const float* W2_l  = W2  + (size_t)l * FF_ * D_;

        // ---- cross attention ----
        ln_kernel<<<B_ * NE_, 256, 0, stream>>>(ne, lnbuf, ln1_g + l * D_, ln1_b + l * D_);
        launch_gemm(stream, 0, lnbuf, D_, Wqkv_l, 3 * D_, bqkv_l, nullptr, nullptr,
                    qb, D_, B_ * NE_, D_, D_);
        launch_gemm(stream, 0, images, D_, Wqkv_l + D_, 3 * D_, bqkv_l + D_, nullptr, nullptr,
                    kb, D_, B_ * HW_, D_, D_);
        launch_gemm(stream, 0, images, D_, Wqkv_l + 2 * D_, 3 * D_, bqkv_l + 2 * D_, nullptr, nullptr,
                    vb, D_, B_ * HW_, D_, D_);
        attn_kernel<<<dim3(NE_ / 32, H_, B_), 256, 0, stream>>>(qb, kb, vb, mask, ctxb);
        launch_gemm(stream, 2, ctxb, D_, Wo_l, D_, bo + l * D_, ne, ls1 + l * D_,
                    ne, D_, B_ * NE_, D_, D_);

        // ---- GAT ----
        ln_kernel<<<B_ * NE_, 256, 0, stream>>>(ne, lnbuf, ln2_g + l * D_, ln2_b + l * D_);
        addenc_kernel<<<(B_ * NE_ * D_) / 256, 256, 0, stream>>>(lnbuf, node_enc, edge_enc, nodes_f, edges_f);
        launch_gemm(stream, 0, nodes_f, D_, Wn1_l, D_, bn1 + l * D_, nullptr, nullptr,
                    gn1, D_, BN_, D_, D_);
        launch_gemm(stream, 0, nodes_f, D_, Wn2_l, D_, bn2 + l * D_, nullptr, nullptr,
                    gn2, D_, BN_, D_, D_);
        launch_gemm(stream, 0, edges_f, D_, We_l, D_, be + l * D_, nullptr, nullptr,
                    hid, D_, BE_, D_, D_);
        hidden_kernel<<<BE_, 256, 0, stream>>>(gn1, gn2, hid, idx0, attn_p + (size_t)l * H_ * DH_, pres);
        segsoft_kernel<<<(BN_ * H_) / 256, 256, 0, stream>>>(pres, csr_off, csr_perm, mseg, denom);
        alpha_kernel<<<(BE_ * H_) / 256, 256, 0, stream>>>(pres, idx0, mseg, denom, alphab);
        launch_gemm(stream, 0, hid, D_, Weo_l, D_, beo + l * D_, nullptr, nullptr,
                    new_edges, D_, BE_, D_, D_);
        vin_kernel<<<(BE_ * D_) / 256, 256, 0, stream>>>(nodes_f, new_edges, idx1, vin);
        launch_gemm(stream, 0, vin, D_, Wno_l, D_, bno + l * D_, nullptr, nullptr,
                    valsb, D_, BE_, D_, D_);
        nodeagg_kernel<<<BN_, 256, 0, stream>>>(valsb, alphab, csr_off, csr_perm, new_nodes);
        gatres_kernel<<<(B_ * NE_ * D_) / 256, 256, 0, stream>>>(ne, new_nodes, new_edges, ls2 + l * D_);

        // ---- FFN ----
        ln_kernel<<<B_ * NE_, 256, 0, stream>>>(ne, lnbuf, ln3_g + l * D_, ln3_b + l * D_);
        launch_gemm(stream, 1, lnbuf, D_, W1_l, FF_, b1 + l * FF_, nullptr, nullptr,
                    ffnh, FF_, B_ * NE_, FF_, D_);
        launch_gemm(stream, 2, ffnh, FF_, W2_l, D_, b2 + l * D_, ne, ls3 + l * D_,
                    ne, D_, B_ * NE_, D_, FF_);
    }
}

// Round 2
// 1352.813 us; speedup vs baseline: 1.4891x; 1.4891x over previous
//
#include <hip/hip_runtime.h>
#include <math.h>

// ---- problem constants ----
static constexpr int B_  = 16;
static constexpr int N_  = 32;
static constexpr int E_  = 256;
static constexpr int D_  = 256;
static constexpr int H_  = 8;
static constexpr int HW_ = 784;
static constexpr int L_  = 4;
static constexpr int DH_ = 32;
static constexpr int FF_ = 1024;
static constexpr int BN_ = 512;
static constexpr int BE_ = 4096;
static constexpr int NE_ = 288;   // N+E
#define SCALE_ 0.17677669529663687f

// per-layer transposed-weight block (bf16 elems)
static constexpr size_t LAYER_W = 1114112;  // 9*65536 + 2*262144
// offsets within a layer block
static constexpr size_t OFF_Q   = 0;
static constexpr size_t OFF_K   = 65536;
static constexpr size_t OFF_V   = 131072;
static constexpr size_t OFF_WO  = 196608;
static constexpr size_t OFF_WN1 = 262144;
static constexpr size_t OFF_WN2 = 327680;
static constexpr size_t OFF_WE  = 393216;
static constexpr size_t OFF_WEO = 458752;
static constexpr size_t OFF_WNO = 524288;
static constexpr size_t OFF_W1  = 589824;
static constexpr size_t OFF_W2  = 851968;

typedef __attribute__((ext_vector_type(8))) short bf16x8;
typedef __attribute__((ext_vector_type(4))) float f32x4;

__device__ __forceinline__ float gelu_f(float x) {
    return 0.5f * x * (1.0f + erff(x * 0.7071067811865476f));
}

__device__ __forceinline__ unsigned short f2bf(float x) {
    unsigned u = __float_as_uint(x);
    u += 0x7FFFu + ((u >> 16) & 1u);   // RNE
    return (unsigned short)(u >> 16);
}
__device__ __forceinline__ unsigned pack2bf(float a, float b) {
    return (unsigned)f2bf(a) | ((unsigned)f2bf(b) << 16);
}

// ---------------- elementwise / LN kernels ----------------

__global__ void concat_kernel(const float* __restrict__ nodes, const float* __restrict__ edges,
                              float* __restrict__ ne) {
    int tid = blockIdx.x * 256 + threadIdx.x;   // B*NE*D
    int d = tid & 255;
    int row = tid >> 8;
    int b = row / NE_, pos = row % NE_;
    float v = (pos < N_) ? nodes[(size_t)(b * N_ + pos) * D_ + d]
                         : edges[(size_t)(b * E_ + (pos - N_)) * D_ + d];
    ne[tid] = v;
}

__global__ __launch_bounds__(256) void ln_kernel(const float* __restrict__ x, float* __restrict__ y,
                                                 const float* __restrict__ g, const float* __restrict__ bta) {
    const int row = blockIdx.x;
    const int d = threadIdx.x;
    float v = x[(size_t)row * D_ + d];
    float s = v, s2 = v * v;
    #pragma unroll
    for (int o = 32; o >= 1; o >>= 1) { s += __shfl_down(s, o); s2 += __shfl_down(s2, o); }
    __shared__ float sh1[4], sh2[4];
    int lane = d & 63, w = d >> 6;
    if (lane == 0) { sh1[w] = s; sh2[w] = s2; }
    __syncthreads();
    if (d == 0) {
        float a = sh1[0] + sh1[1] + sh1[2] + sh1[3];
        float c = sh2[0] + sh2[1] + sh2[2] + sh2[3];
        sh1[0] = a; sh2[0] = c;
    }
    __syncthreads();
    float mean = sh1[0] * (1.0f / D_);
    float var  = sh2[0] * (1.0f / D_) - mean * mean;
    float rstd = rsqrtf(var + 1e-5f);
    y[(size_t)row * D_ + d] = (v - mean) * rstd * g[d] + bta[d];
}

// ---------------- weight transpose+cast: W[K,N] f32 -> Wt[N,K] bf16 ----------------
// 1088 tiles/layer * 4 layers; tile = 32x32
__global__ __launch_bounds__(256) void wtrans_kernel(
    const float* __restrict__ Wqkv, const float* __restrict__ Wo,
    const float* __restrict__ Wn1,  const float* __restrict__ Wn2,
    const float* __restrict__ We,   const float* __restrict__ Weo,
    const float* __restrict__ Wno,  const float* __restrict__ W1,
    const float* __restrict__ W2,   unsigned short* __restrict__ wT)
{
    const int bid = blockIdx.x;
    const int l = bid / 1088;
    int tl = bid % 1088;
    const float* src; int ld, K, Nn; unsigned short* dst;
    if (tl < 576) {
        int mid = tl >> 6; tl &= 63;
        K = 256; Nn = 256;
        if (mid < 3) {
            src = Wqkv + (size_t)l * 256 * 768 + mid * 256; ld = 768;
            dst = wT + (size_t)l * LAYER_W + (size_t)mid * 65536;
        } else {
            const float* bases[6] = {Wo, Wn1, Wn2, We, Weo, Wno};
            src = bases[mid - 3] + (size_t)l * 65536; ld = 256;
            dst = wT + (size_t)l * LAYER_W + OFF_WO + (size_t)(mid - 3) * 65536;
        }
    } else if (tl < 832) {
        tl -= 576; K = 256; Nn = 1024;
        src = W1 + (size_t)l * 262144; ld = 1024;
        dst = wT + (size_t)l * LAYER_W + OFF_W1;
    } else {
        tl -= 832; K = 1024; Nn = 256;
        src = W2 + (size_t)l * 262144; ld = 256;
        dst = wT + (size_t)l * LAYER_W + OFF_W2;
    }
    const int ntn = Nn >> 5;
    const int k0 = (tl / ntn) << 5, n0 = (tl % ntn) << 5;
    __shared__ float ts[32][33];
    const int t = threadIdx.x;
    const int kl = t >> 5, nl = t & 31;
    #pragma unroll
    for (int rr = 0; rr < 4; ++rr)
        ts[kl + rr * 8][nl] = src[(size_t)(k0 + kl + rr * 8) * ld + n0 + nl];
    __syncthreads();
    const int onl = t >> 3, okl = (t & 7) << 2;
    ushort4 o;
    o.x = f2bf(ts[okl + 0][onl]); o.y = f2bf(ts[okl + 1][onl]);
    o.z = f2bf(ts[okl + 2][onl]); o.w = f2bf(ts[okl + 3][onl]);
    *(ushort4*)&dst[(size_t)(n0 + onl) * K + k0 + okl] = o;
}

// ---------------- MFMA GEMM: C[M,N] = epi(A[M,K]_f32 @ Bt[N,K]_bf16^T + bias) ----------------
// MODE 0: +bias ; MODE 1: gelu(+bias) ; MODE 2: res + ls*(+bias)
// tile 64x64, BK=64, 256 threads (4 waves, 2x2 wave grid, each wave 32x32 via 2x2 mfma frags)
template<int MODE>
__global__ __launch_bounds__(256) void mgemm_kernel(
    const float* __restrict__ A, int lda,
    const unsigned short* __restrict__ Bt,
    const float* __restrict__ bias,
    const float* __restrict__ res,
    const float* __restrict__ ls,
    float* __restrict__ C, int ldc, int K)
{
    __shared__ unsigned short As[64][72];
    __shared__ unsigned short Bs[64][72];
    const int m0 = blockIdx.y * 64, n0 = blockIdx.x * 64;
    const int t = threadIdx.x;
    const int l = t & 63, w = t >> 6;
    const int wr = (w >> 1) * 32, wc = (w & 1) * 32;
    const int srow = t >> 2, skc = (t & 3) * 16;
    const int frow = l & 15, kg = l >> 4;
    f32x4 acc[2][2];
    acc[0][0] = (f32x4){0.f,0.f,0.f,0.f}; acc[0][1] = acc[0][0];
    acc[1][0] = acc[0][0];                acc[1][1] = acc[0][0];
    for (int k0 = 0; k0 < K; k0 += 64) {
        const float* ap = A + (size_t)(m0 + srow) * lda + k0 + skc;
        float4 a0 = *(const float4*)(ap + 0);
        float4 a1 = *(const float4*)(ap + 4);
        float4 a2 = *(const float4*)(ap + 8);
        float4 a3 = *(const float4*)(ap + 12);
        const unsigned short* bp = Bt + (size_t)(n0 + srow) * K + k0 + skc;
        uint4 bq0 = *(const uint4*)(bp);
        uint4 bq1 = *(const uint4*)(bp + 8);
        __syncthreads();
        uint4 wa0 = make_uint4(pack2bf(a0.x, a0.y), pack2bf(a0.z, a0.w),
                               pack2bf(a1.x, a1.y), pack2bf(a1.z, a1.w));
        uint4 wa1 = make_uint4(pack2bf(a2.x, a2.y), pack2bf(a2.z, a2.w),
                               pack2bf(a3.x, a3.y), pack2bf(a3.z, a3.w));
        *(uint4*)&As[srow][skc]     = wa0;
        *(uint4*)&As[srow][skc + 8] = wa1;
        *(uint4*)&Bs[srow][skc]     = bq0;
        *(uint4*)&Bs[srow][skc + 8] = bq1;
        __syncthreads();
        #pragma unroll
        for (int kk = 0; kk < 2; ++kk) {
            bf16x8 af0 = *(const bf16x8*)&As[wr + frow][kk * 32 + kg * 8];
            bf16x8 af1 = *(const bf16x8*)&As[wr + 16 + frow][kk * 32 + kg * 8];
            bf16x8 bf0 = *(const bf16x8*)&Bs[wc + frow][kk * 32 + kg * 8];
            bf16x8 bf1 = *(const bf16x8*)&Bs[wc + 16 + frow][kk * 32 + kg * 8];
            acc[0][0] = __builtin_amdgcn_mfma_f32_16x16x32_bf16(af0, bf0, acc[0][0], 0, 0, 0);
            acc[0][1] = __builtin_amdgcn_mfma_f32_16x16x32_bf16(af0, bf1, acc[0][1], 0, 0, 0);
            acc[1][0] = __builtin_amdgcn_mfma_f32_16x16x32_bf16(af1, bf0, acc[1][0], 0, 0, 0);
            acc[1][1] = __builtin_amdgcn_mfma_f32_16x16x32_bf16(af1, bf1, acc[1][1], 0, 0, 0);
        }
    }
    // C/D layout: col = lane&15, row = (lane>>4)*4 + reg
    #pragma unroll
    for (int fr = 0; fr < 2; ++fr) {
        #pragma unroll
        for (int fc = 0; fc < 2; ++fc) {
            int n = n0 + wc + fc * 16 + frow;
            float bv = bias[n];
            float lv = (MODE == 2) ? ls[n] : 0.f;
            #pragma unroll
            for (int rg = 0; rg < 4; ++rg) {
                int m = m0 + wr + fr * 16 + kg * 4 + rg;
                float vv = acc[fr][fc][rg] + bv;
                if (MODE == 1) vv = gelu_f(vv);
                if (MODE == 2) vv = res[(size_t)m * ldc + n] + lv * vv;
                C[(size_t)m * ldc + n] = vv;
            }
        }
    }
}

// ---------------- flash attention ----------------
// grid (9, H, B), block 256. 32 q-rows/block, 8 lanes per row, KV chunks of 64.
// Mask tile staged to LDS (coalesced float4); next chunk register-prefetched.
__global__ __launch_bounds__(256) void attn_kernel(
    const float* __restrict__ q, const float* __restrict__ k,
    const float* __restrict__ v, const float* __restrict__ mask,
    float* __restrict__ ctx)
{
    const int qt = blockIdx.x, h = blockIdx.y, b = blockIdx.z;
    const int q0 = qt * 32;
    const int t = threadIdx.x;
    const int r = t >> 3, j = t & 7;
    __shared__ float Ks[64][36];
    __shared__ float Vs[64][36];
    __shared__ float Ms[32][68];
    float qreg[32];
    {
        const float* qrow = q + (size_t)(b * NE_ + q0 + r) * D_ + h * DH_;
        #pragma unroll
        for (int i = 0; i < 8; ++i) {
            float4 t4 = *(const float4*)(qrow + i * 4);
            qreg[i * 4 + 0] = t4.x; qreg[i * 4 + 1] = t4.y;
            qreg[i * 4 + 2] = t4.z; qreg[i * 4 + 3] = t4.w;
        }
    }
    const int srow = t >> 2, scc = (t & 3) * 8;
    const int mcc = (t & 7) * 8;
    const float* kbase = k + ((size_t)b * HW_) * D_ + h * DH_ + scc;
    const float* vbase = v + ((size_t)b * HW_) * D_ + h * DH_ + scc;
    const float* mbase = mask + ((size_t)(b * H_ + h) * NE_ + q0 + r) * HW_;

    float4 pk0, pk1, pv0, pv1, pm0, pm1;
    auto issue = [&](int c0) {
        int rr = c0 + srow; if (rr >= HW_) rr = HW_ - 1;
        const float* kp = kbase + (size_t)rr * D_;
        const float* vp = vbase + (size_t)rr * D_;
        pk0 = *(const float4*)(kp);     pk1 = *(const float4*)(kp + 4);
        pv0 = *(const float4*)(vp);     pv1 = *(const float4*)(vp + 4);
        int mc = c0 + mcc;
        if (mc + 8 <= HW_) {
            pm0 = *(const float4*)(mbase + mc);
            pm1 = *(const float4*)(mbase + mc + 4);
        } else {
            pm0 = make_float4(0.f, 0.f, 0.f, 0.f); pm1 = pm0;
        }
    };
    issue(0);

    float m_i = -INFINITY, l_i = 0.f;
    float accv[32];
    #pragma unroll
    for (int i = 0; i < 32; ++i) accv[i] = 0.f;

    for (int c0 = 0; c0 < HW_; c0 += 64) {
        __syncthreads();
        *(float4*)&Ks[srow][scc]     = pk0; *(float4*)&Ks[srow][scc + 4] = pk1;
        *(float4*)&Vs[srow][scc]     = pv0; *(float4*)&Vs[srow][scc + 4] = pv1;
        *(float4*)&Ms[r][mcc]        = pm0; *(float4*)&Ms[r][mcc + 4]    = pm1;
        __syncthreads();
        if (c0 + 64 < HW_) issue(c0 + 64);

        float sc[8];
        #pragma unroll
        for (int s = 0; s < 8; ++s) {
            int kk = j + s * 8;
            float a = 0.f;
            #pragma unroll
            for (int i = 0; i < 8; ++i) {
                float4 k4 = *(const float4*)&Ks[kk][i * 4];
                a += qreg[i * 4] * k4.x + qreg[i * 4 + 1] * k4.y
                   + qreg[i * 4 + 2] * k4.z + qreg[i * 4 + 3] * k4.w;
            }
            int kabs = c0 + kk;
            sc[s] = (kabs < HW_) ? (a * SCALE_ + Ms[r][kk]) : -INFINITY;
        }
        float mloc = sc[0];
        #pragma unroll
        for (int s = 1; s < 8; ++s) mloc = fmaxf(mloc, sc[s]);
        #pragma unroll
        for (int o = 1; o < 8; o <<= 1) mloc = fmaxf(mloc, __shfl_xor(mloc, o));
        float m_new = fmaxf(m_i, mloc);
        float scl = expf(m_i - m_new);    // first chunk: exp(-inf)=0
        float p[8]; float lloc = 0.f;
        #pragma unroll
        for (int s = 0; s < 8; ++s) { p[s] = expf(sc[s] - m_new); lloc += p[s]; }
        #pragma unroll
        for (int o = 1; o < 8; o <<= 1) lloc += __shfl_xor(lloc, o);
        l_i = l_i * scl + lloc;
        m_i = m_new;
        #pragma unroll
        for (int i = 0; i < 32; ++i) accv[i] *= scl;
        #pragma unroll
        for (int s = 0; s < 8; ++s) {
            int kk = j + s * 8;
            float pv = p[s];
            #pragma unroll
            for (int i = 0; i < 8; ++i) {
                float4 v4 = *(const float4*)&Vs[kk][i * 4];
                accv[i * 4 + 0] += pv * v4.x; accv[i * 4 + 1] += pv * v4.y;
                accv[i * 4 + 2] += pv * v4.z; accv[i * 4 + 3] += pv * v4.w;
            }
        }
    }
    #pragma unroll
    for (int i = 0; i < 32; ++i) {
        float a = accv[i];
        a += __shfl_xor(a, 1); a += __shfl_xor(a, 2); a += __shfl_xor(a, 4);
        accv[i] = a;
    }
    float inv_l = 1.0f / l_i;
    float* crow = ctx + (size_t)(b * NE_ + q0 + r) * D_ + h * DH_ + j * 4;
    float4 o4 = make_float4(accv[j * 4] * inv_l, accv[j * 4 + 1] * inv_l,
                            accv[j * 4 + 2] * inv_l, accv[j * 4 + 3] * inv_l);
    *(float4*)crow = o4;
}

// ---------------- GAT kernels ----------------

__global__ void addenc_kernel(const float* __restrict__ ln, const float* __restrict__ node_enc,
                              const float* __restrict__ edge_enc,
                              float* __restrict__ nodes_f, float* __restrict__ edges_f) {
    int tid = blockIdx.x * 256 + threadIdx.x;   // B*NE*D
    int d = tid & 255;
    int row = tid >> 8;
    int b = row / NE_, pos = row % NE_;
    float v = ln[tid];
    if (pos < N_) {
        int rn = b * N_ + pos;
        nodes_f[(size_t)rn * D_ + d] = v + node_enc[(size_t)rn * D_ + d];
    } else {
        int re = b * E_ + (pos - N_);
        edges_f[(size_t)re * D_ + d] = v + edge_enc[(size_t)re * D_ + d];
    }
}

__global__ __launch_bounds__(256) void hidden_kernel(
    const float* __restrict__ gn1, const float* __restrict__ gn2,
    float* __restrict__ hid, const int* __restrict__ idx0,
    const float* __restrict__ attn_p_l, float* __restrict__ pres) {
    int e = blockIdx.x;
    int d = threadIdx.x;
    int n = idx0[e];
    float x = hid[(size_t)e * D_ + d] + gn1[(size_t)n * D_ + d] + gn2[(size_t)n * D_ + d];
    float hv = gelu_f(x);
    hid[(size_t)e * D_ + d] = hv;
    float pr = hv * attn_p_l[d];
    #pragma unroll
    for (int o = 1; o < 32; o <<= 1) pr += __shfl_xor(pr, o);
    if ((d & 31) == 0) pres[e * H_ + (d >> 5)] = pr;
}

__global__ void segsoft_kernel(const float* __restrict__ pres, const int* __restrict__ csr_off,
                               const int* __restrict__ csr_perm,
                               float* __restrict__ mseg, float* __restrict__ denom) {
    int tid = blockIdx.x * 256 + threadIdx.x;   // BN*H
    int n = tid >> 3, h = tid & 7;
    int s = csr_off[n], e2 = csr_off[n + 1];
    float mx = -INFINITY;
    for (int i = s; i < e2; ++i) mx = fmaxf(mx, pres[csr_perm[i] * H_ + h]);
    float sum = 0.f;
    for (int i = s; i < e2; ++i) sum += expf(pres[csr_perm[i] * H_ + h] - mx);
    mseg[tid] = mx;
    denom[tid] = sum;
}

__global__ void alpha_kernel(const float* __restrict__ pres, const int* __restrict__ idx0,
                             const float* __restrict__ mseg, const float* __restrict__ denom,
                             float* __restrict__ alpha) {
    int tid = blockIdx.x * 256 + threadIdx.x;   // BE*H
    int e = tid >> 3, h = tid & 7;
    int n = idx0[e];
    alpha[tid] = expf(pres[tid] - mseg[n * H_ + h]) / denom[n * H_ + h];
}

__global__ void vin_kernel(const float* __restrict__ nodes_f, const float* __restrict__ new_edges,
                           const int* __restrict__ idx1, float* __restrict__ vin) {
    int tid = blockIdx.x * 256 + threadIdx.x;   // BE*D
    int e = tid >> 8, d = tid & 255;
    vin[tid] = nodes_f[(size_t)idx1[e] * D_ + d] + new_edges[tid];
}

__global__ __launch_bounds__(256) void nodeagg_kernel(
    const float* __restrict__ vals, const float* __restrict__ alpha,
    const int* __restrict__ csr_off, const int* __restrict__ csr_perm,
    float* __restrict__ new_nodes) {
    int n = blockIdx.x;
    int d = threadIdx.x;
    int s = csr_off[n], e2 = csr_off[n + 1];
    int h = d >> 5;
    float acc = 0.f;
    for (int i = s; i < e2; ++i) {
        int e = csr_perm[i];
        acc += vals[(size_t)e * D_ + d] * alpha[e * H_ + h];
    }
    new_nodes[(size_t)n * D_ + d] = acc;
}

__global__ void gatres_kernel(float* __restrict__ ne, const float* __restrict__ new_nodes,
                              const float* __restrict__ new_edges, const float* __restrict__ ls2l) {
    int tid = blockIdx.x * 256 + threadIdx.x;   // B*NE*D
    int d = tid & 255;
    int row = tid >> 8;
    int b = row / NE_, pos = row % NE_;
    float g = (pos < N_) ? new_nodes[(size_t)(b * N_ + pos) * D_ + d]
                         : new_edges[(size_t)(b * E_ + (pos - N_)) * D_ + d];
    ne[tid] += ls2l[d] * g;
}

// ---------------- CSR build (deterministic) ----------------

__global__ void zero_counts(int* counts) {
    int t = blockIdx.x * 256 + threadIdx.x;
    if (t < BN_) counts[t] = 0;
}

__global__ void csr_count(const int* __restrict__ idx0, int* __restrict__ counts) {
    int e = blockIdx.x * 256 + threadIdx.x;
    if (e < BE_) atomicAdd(&counts[idx0[e]], 1);
}

__global__ __launch_bounds__(512) void csr_scan(const int* __restrict__ counts, int* __restrict__ csr_off) {
    __shared__ int buf[BN_];
    int t = threadIdx.x;
    int c = counts[t];
    buf[t] = c;
    __syncthreads();
    for (int o = 1; o < BN_; o <<= 1) {
        int add = (t >= o) ? buf[t - o] : 0;
        __syncthreads();
        buf[t] += add;
        __syncthreads();
    }
    csr_off[t] = buf[t] - c;
    if (t == BN_ - 1) csr_off[BN_] = buf[t];
}

__global__ __launch_bounds__(64) void csr_fill(const int* __restrict__ idx0,
                                               const int* __restrict__ csr_off,
                                               int* __restrict__ csr_perm) {
    int n = blockIdx.x;
    int lane = threadIdx.x;
    int w = csr_off[n];
    for (int c0 = 0; c0 < BE_; c0 += 64) {
        int e = c0 + lane;
        bool m = (idx0[e] == n);
        unsigned long long bal = __ballot(m);
        if (m) {
            int pre = __popcll(bal & ((1ull << lane) - 1ull));
            csr_perm[w + pre] = e;
        }
        w += __popcll(bal);
    }
}

// ---------------- host orchestration ----------------

static void launch_mgemm(hipStream_t s, int mode,
                         const float* A, int lda, const unsigned short* Bt,
                         const float* bias, const float* res, const float* ls,
                         float* C, int ldc, int M, int N, int K) {
    dim3 g(N / 64, M / 64);
    if (mode == 0)      mgemm_kernel<0><<<g, 256, 0, s>>>(A, lda, Bt, bias, res, ls, C, ldc, K);
    else if (mode == 1) mgemm_kernel<1><<<g, 256, 0, s>>>(A, lda, Bt, bias, res, ls, C, ldc, K);
    else                mgemm_kernel<2><<<g, 256, 0, s>>>(A, lda, Bt, bias, res, ls, C, ldc, K);
}

extern "C" void kernel_launch(void* const* d_in, const int* in_sizes, int n_in,
                              void* d_out, int out_size, void* d_ws, size_t ws_size,
                              hipStream_t stream) {
    const float* nodes    = (const float*)d_in[0];
    const float* edges    = (const float*)d_in[1];
    const float* images   = (const float*)d_in[2];
    const float* mask     = (const float*)d_in[3];
    const float* node_enc = (const float*)d_in[4];
    const float* edge_enc = (const float*)d_in[5];
    const float* ln1_g = (const float*)d_in[6];
    const float* ln1_b = (const float*)d_in[7];
    const float* Wqkv  = (const float*)d_in[8];
    const float* bqkv  = (const float*)d_in[9];
    const float* Wo    = (const float*)d_in[10];
    const float* bo    = (const float*)d_in[11];
    const float* ls1   = (const float*)d_in[12];
    const float* ln2_g = (const float*)d_in[13];
    const float* ln2_b = (const float*)d_in[14];
    const float* Wn1   = (const float*)d_in[15];
    const float* bn1   = (const float*)d_in[16];
    const float* Wn2   = (const float*)d_in[17];
    const float* bn2   = (const float*)d_in[18];
    const float* We    = (const float*)d_in[19];
    const float* be    = (const float*)d_in[20];
    const float* attn_p= (const float*)d_in[21];
    const float* Weo   = (const float*)d_in[22];
    const float* beo   = (const float*)d_in[23];
    const float* Wno   = (const float*)d_in[24];
    const float* bno   = (const float*)d_in[25];
    const float* ls2   = (const float*)d_in[26];
    const float* ln3_g = (const float*)d_in[27];
    const float* ln3_b = (const float*)d_in[28];
    const float* W1    = (const float*)d_in[29];
    const float* b1    = (const float*)d_in[30];
    const float* W2    = (const float*)d_in[31];
    const float* b2    = (const float*)d_in[32];
    const float* ls3   = (const float*)d_in[33];
    const int*   edge_index = (const int*)d_in[34];
    const int* idx0 = edge_index;
    const int* idx1 = edge_index + BE_;

    float* ne = (float*)d_out;   // d_out doubles as the running `ne` buffer

    float* cur = (float*)d_ws;
    auto alloc = [&](size_t nfl) { float* p = cur; cur += nfl; return p; };
    float* lnbuf    = alloc((size_t)B_ * NE_ * D_);
    float* qb       = alloc((size_t)B_ * NE_ * D_);
    float* kb       = alloc((size_t)B_ * HW_ * D_);
    float* vb       = alloc((size_t)B_ * HW_ * D_);
    float* ffnh     = kb;   // alias: k/v dead by FFN time
    float* ctxb     = alloc((size_t)B_ * NE_ * D_);
    float* nodes_f  = alloc((size_t)BN_ * D_);
    float* edges_f  = alloc((size_t)BE_ * D_);
    float* gn1      = alloc((size_t)BN_ * D_);
    float* gn2      = alloc((size_t)BN_ * D_);
    float* hid      = alloc((size_t)BE_ * D_);
    float* pres     = alloc((size_t)BE_ * H_);
    float* mseg     = alloc((size_t)BN_ * H_);
    float* denom    = alloc((size_t)BN_ * H_);
    float* alphab   = alloc((size_t)BE_ * H_);
    float* new_edges= alloc((size_t)BE_ * D_);
    float* vin      = alloc((size_t)BE_ * D_);
    float* valsb    = alloc((size_t)BE_ * D_);
    float* new_nodes= alloc((size_t)BN_ * D_);
    int* counts   = (int*)cur; cur += BN_;
    int* csr_off  = (int*)cur; cur += BN_ + 4;
    int* csr_perm = (int*)cur; cur += BE_;
    cur = (float*)(((uintptr_t)cur + 255) & ~(uintptr_t)255);
    unsigned short* wT = (unsigned short*)cur;   // 4 * LAYER_W bf16

    // ---- once-per-call preprocessing ----
    wtrans_kernel<<<4 * 1088, 256, 0, stream>>>(Wqkv, Wo, Wn1, Wn2, We, Weo, Wno, W1, W2, wT);
    zero_counts<<<2, 256, 0, stream>>>(counts);
    csr_count<<<BE_ / 256, 256, 0, stream>>>(idx0, counts);
    csr_scan<<<1, 512, 0, stream>>>(counts, csr_off);
    csr_fill<<<BN_, 64, 0, stream>>>(idx0, csr_off, csr_perm);
    concat_kernel<<<(B_ * NE_ * D_) / 256, 256, 0, stream>>>(nodes, edges, ne);

    for (int l = 0; l < L_; ++l) {
        const unsigned short* wTl = wT + (size_t)l * LAYER_W;
        const float* bqkv_l = bqkv + (size_t)l * 3 * D_;

        // ---- cross attention ----
        ln_kernel<<<B_ * NE_, 256, 0, stream>>>(ne, lnbuf, ln1_g + l * D_, ln1_b + l * D_);
        launch_mgemm(stream, 0, lnbuf, D_, wTl + OFF_Q, bqkv_l, nullptr, nullptr,
                     qb, D_, B_ * NE_, D_, D_);
        launch_mgemm(stream, 0, images, D_, wTl + OFF_K, bqkv_l + D_, nullptr, nullptr,
                     kb, D_, B_ * HW_, D_, D_);
        launch_mgemm(stream, 0, images, D_, wTl + OFF_V, bqkv_l + 2 * D_, nullptr, nullptr,
                     vb, D_, B_ * HW_, D_, D_);
        attn_kernel<<<dim3(NE_ / 32, H_, B_), 256, 0, stream>>>(qb, kb, vb, mask, ctxb);
        launch_mgemm(stream, 2, ctxb, D_, wTl + OFF_WO, bo + l * D_, ne, ls1 + l * D_,
                     ne, D_, B_ * NE_, D_, D_);

        // ---- GAT ----
        ln_kernel<<<B_ * NE_, 256, 0, stream>>>(ne, lnbuf, ln2_g + l * D_, ln2_b + l * D_);
        addenc_kernel<<<(B_ * NE_ * D_) / 256, 256, 0, stream>>>(lnbuf, node_enc, edge_enc, nodes_f, edges_f);
        launch_mgemm(stream, 0, nodes_f, D_, wTl + OFF_WN1, bn1 + l * D_, nullptr, nullptr,
                     gn1, D_, BN_, D_, D_);
        launch_mgemm(stream, 0, nodes_f, D_, wTl + OFF_WN2, bn2 + l * D_, nullptr, nullptr,
                     gn2, D_, BN_, D_, D_);
        launch_mgemm(stream, 0, edges_f, D_, wTl + OFF_WE, be + l * D_, nullptr, nullptr,
                     hid, D_, BE_, D_, D_);
        hidden_kernel<<<BE_, 256, 0, stream>>>(gn1, gn2, hid, idx0, attn_p + (size_t)l * H_ * DH_, pres);
        segsoft_kernel<<<(BN_ * H_) / 256, 256, 0, stream>>>(pres, csr_off, csr_perm, mseg, denom);
        alpha_kernel<<<(BE_ * H_) / 256, 256, 0, stream>>>(pres, idx0, mseg, denom, alphab);
        launch_mgemm(stream, 0, hid, D_, wTl + OFF_WEO, beo + l * D_, nullptr, nullptr,
                     new_edges, D_, BE_, D_, D_);
        vin_kernel<<<(BE_ * D_) / 256, 256, 0, stream>>>(nodes_f, new_edges, idx1, vin);
        launch_mgemm(stream, 0, vin, D_, wTl + OFF_WNO, bno + l * D_, nullptr, nullptr,
                     valsb, D_, BE_, D_, D_);
        nodeagg_kernel<<<BN_, 256, 0, stream>>>(valsb, alphab, csr_off, csr_perm, new_nodes);
        gatres_kernel<<<(B_ * NE_ * D_) / 256, 256, 0, stream>>>(ne, new_nodes, new_edges, ls2 + l * D_);

        // ---- FFN ----
        ln_kernel<<<B_ * NE_, 256, 0, stream>>>(ne, lnbuf, ln3_g + l * D_, ln3_b + l * D_);
        launch_mgemm(stream, 1, lnbuf, D_, wTl + OFF_W1, b1 + l * FF_, nullptr, nullptr,
                     ffnh, FF_, B_ * NE_, FF_, D_);
        launch_mgemm(stream, 2, ffnh, FF_, wTl + OFF_W2, b2 + l * D_, ne, ls3 + l * D_,
                     ne, D_, B_ * NE_, D_, FF_);
    }
}

// Round 3
// 864.015 us; speedup vs baseline: 2.3315x; 1.5657x over previous
//
#include <hip/hip_runtime.h>
#include <math.h>

// ---- problem constants ----
static constexpr int B_  = 16;
static constexpr int N_  = 32;
static constexpr int E_  = 256;
static constexpr int D_  = 256;
static constexpr int H_  = 8;
static constexpr int HW_ = 784;
static constexpr int L_  = 4;
static constexpr int DH_ = 32;
static constexpr int FF_ = 1024;
static constexpr int BN_ = 512;
static constexpr int BE_ = 4096;
static constexpr int NE_ = 288;   // N+E
#define SCALE_ 0.17677669529663687f

// per-layer transposed-weight block (bf16 elems)
static constexpr size_t LAYER_W = 1114112;  // 9*65536 + 2*262144
static constexpr size_t OFF_Q   = 0;
static constexpr size_t OFF_K   = 65536;
static constexpr size_t OFF_V   = 131072;
static constexpr size_t OFF_WO  = 196608;
static constexpr size_t OFF_WN1 = 262144;
static constexpr size_t OFF_WN2 = 327680;
static constexpr size_t OFF_WE  = 393216;
static constexpr size_t OFF_WEO = 458752;
static constexpr size_t OFF_WNO = 524288;
static constexpr size_t OFF_W1  = 589824;
static constexpr size_t OFF_W2  = 851968;

typedef __attribute__((ext_vector_type(8))) short bf16x8;
typedef __attribute__((ext_vector_type(4))) float f32x4;

union U4H8 { uint4 u; bf16x8 h; };

__device__ __forceinline__ float gelu_f(float x) {
    return 0.5f * x * (1.0f + erff(x * 0.7071067811865476f));
}

__device__ __forceinline__ unsigned short f2bf(float x) {
    unsigned u = __float_as_uint(x);
    u += 0x7FFFu + ((u >> 16) & 1u);   // RNE
    return (unsigned short)(u >> 16);
}
__device__ __forceinline__ unsigned pack2bf(float a, float b) {
    return (unsigned)f2bf(a) | ((unsigned)f2bf(b) << 16);
}

// ---------------- elementwise / LN kernels ----------------

__global__ void concat_kernel(const float* __restrict__ nodes, const float* __restrict__ edges,
                              float* __restrict__ ne) {
    int tid = blockIdx.x * 256 + threadIdx.x;   // B*NE*D
    int d = tid & 255;
    int row = tid >> 8;
    int b = row / NE_, pos = row % NE_;
    float v = (pos < N_) ? nodes[(size_t)(b * N_ + pos) * D_ + d]
                         : edges[(size_t)(b * E_ + (pos - N_)) * D_ + d];
    ne[tid] = v;
}

__global__ __launch_bounds__(256) void ln_kernel(const float* __restrict__ x, float* __restrict__ y,
                                                 const float* __restrict__ g, const float* __restrict__ bta) {
    const int row = blockIdx.x;
    const int d = threadIdx.x;
    float v = x[(size_t)row * D_ + d];
    float s = v, s2 = v * v;
    #pragma unroll
    for (int o = 32; o >= 1; o >>= 1) { s += __shfl_down(s, o); s2 += __shfl_down(s2, o); }
    __shared__ float sh1[4], sh2[4];
    int lane = d & 63, w = d >> 6;
    if (lane == 0) { sh1[w] = s; sh2[w] = s2; }
    __syncthreads();
    if (d == 0) {
        float a = sh1[0] + sh1[1] + sh1[2] + sh1[3];
        float c = sh2[0] + sh2[1] + sh2[2] + sh2[3];
        sh1[0] = a; sh2[0] = c;
    }
    __syncthreads();
    float mean = sh1[0] * (1.0f / D_);
    float var  = sh2[0] * (1.0f / D_) - mean * mean;
    float rstd = rsqrtf(var + 1e-5f);
    y[(size_t)row * D_ + d] = (v - mean) * rstd * g[d] + bta[d];
}

// ---------------- weight transpose+cast: W[K,N] f32 -> Wt[N,K] bf16 ----------------
__global__ __launch_bounds__(256) void wtrans_kernel(
    const float* __restrict__ Wqkv, const float* __restrict__ Wo,
    const float* __restrict__ Wn1,  const float* __restrict__ Wn2,
    const float* __restrict__ We,   const float* __restrict__ Weo,
    const float* __restrict__ Wno,  const float* __restrict__ W1,
    const float* __restrict__ W2,   unsigned short* __restrict__ wT)
{
    const int bid = blockIdx.x;
    const int l = bid / 1088;
    int tl = bid % 1088;
    const float* src; int ld, K, Nn; unsigned short* dst;
    if (tl < 576) {
        int mid = tl >> 6; tl &= 63;
        K = 256; Nn = 256;
        if (mid < 3) {
            src = Wqkv + (size_t)l * 256 * 768 + mid * 256; ld = 768;
            dst = wT + (size_t)l * LAYER_W + (size_t)mid * 65536;
        } else {
            const float* bases[6] = {Wo, Wn1, Wn2, We, Weo, Wno};
            src = bases[mid - 3] + (size_t)l * 65536; ld = 256;
            dst = wT + (size_t)l * LAYER_W + OFF_WO + (size_t)(mid - 3) * 65536;
        }
    } else if (tl < 832) {
        tl -= 576; K = 256; Nn = 1024;
        src = W1 + (size_t)l * 262144; ld = 1024;
        dst = wT + (size_t)l * LAYER_W + OFF_W1;
    } else {
        tl -= 832; K = 1024; Nn = 256;
        src = W2 + (size_t)l * 262144; ld = 256;
        dst = wT + (size_t)l * LAYER_W + OFF_W2;
    }
    const int ntn = Nn >> 5;
    const int k0 = (tl / ntn) << 5, n0 = (tl % ntn) << 5;
    __shared__ float ts[32][33];
    const int t = threadIdx.x;
    const int kl = t >> 5, nl = t & 31;
    #pragma unroll
    for (int rr = 0; rr < 4; ++rr)
        ts[kl + rr * 8][nl] = src[(size_t)(k0 + kl + rr * 8) * ld + n0 + nl];
    __syncthreads();
    const int onl = t >> 3, okl = (t & 7) << 2;
    ushort4 o;
    o.x = f2bf(ts[okl + 0][onl]); o.y = f2bf(ts[okl + 1][onl]);
    o.z = f2bf(ts[okl + 2][onl]); o.w = f2bf(ts[okl + 3][onl]);
    *(ushort4*)&dst[(size_t)(n0 + onl) * K + k0 + okl] = o;
}

// ---------------- MFMA GEMM ----------------
template<int MODE>
__global__ __launch_bounds__(256) void mgemm_kernel(
    const float* __restrict__ A, int lda,
    const unsigned short* __restrict__ Bt,
    const float* __restrict__ bias,
    const float* __restrict__ res,
    const float* __restrict__ ls,
    float* __restrict__ C, int ldc, int K)
{
    __shared__ unsigned short As[64][72];
    __shared__ unsigned short Bs[64][72];
    const int m0 = blockIdx.y * 64, n0 = blockIdx.x * 64;
    const int t = threadIdx.x;
    const int l = t & 63, w = t >> 6;
    const int wr = (w >> 1) * 32, wc = (w & 1) * 32;
    const int srow = t >> 2, skc = (t & 3) * 16;
    const int frow = l & 15, kg = l >> 4;
    f32x4 acc[2][2];
    acc[0][0] = (f32x4){0.f,0.f,0.f,0.f}; acc[0][1] = acc[0][0];
    acc[1][0] = acc[0][0];                acc[1][1] = acc[0][0];
    for (int k0 = 0; k0 < K; k0 += 64) {
        const float* ap = A + (size_t)(m0 + srow) * lda + k0 + skc;
        float4 a0 = *(const float4*)(ap + 0);
        float4 a1 = *(const float4*)(ap + 4);
        float4 a2 = *(const float4*)(ap + 8);
        float4 a3 = *(const float4*)(ap + 12);
        const unsigned short* bp = Bt + (size_t)(n0 + srow) * K + k0 + skc;
        uint4 bq0 = *(const uint4*)(bp);
        uint4 bq1 = *(const uint4*)(bp + 8);
        __syncthreads();
        uint4 wa0 = make_uint4(pack2bf(a0.x, a0.y), pack2bf(a0.z, a0.w),
                               pack2bf(a1.x, a1.y), pack2bf(a1.z, a1.w));
        uint4 wa1 = make_uint4(pack2bf(a2.x, a2.y), pack2bf(a2.z, a2.w),
                               pack2bf(a3.x, a3.y), pack2bf(a3.z, a3.w));
        *(uint4*)&As[srow][skc]     = wa0;
        *(uint4*)&As[srow][skc + 8] = wa1;
        *(uint4*)&Bs[srow][skc]     = bq0;
        *(uint4*)&Bs[srow][skc + 8] = bq1;
        __syncthreads();
        #pragma unroll
        for (int kk = 0; kk < 2; ++kk) {
            bf16x8 af0 = *(const bf16x8*)&As[wr + frow][kk * 32 + kg * 8];
            bf16x8 af1 = *(const bf16x8*)&As[wr + 16 + frow][kk * 32 + kg * 8];
            bf16x8 bf0 = *(const bf16x8*)&Bs[wc + frow][kk * 32 + kg * 8];
            bf16x8 bf1 = *(const bf16x8*)&Bs[wc + 16 + frow][kk * 32 + kg * 8];
            acc[0][0] = __builtin_amdgcn_mfma_f32_16x16x32_bf16(af0, bf0, acc[0][0], 0, 0, 0);
            acc[0][1] = __builtin_amdgcn_mfma_f32_16x16x32_bf16(af0, bf1, acc[0][1], 0, 0, 0);
            acc[1][0] = __builtin_amdgcn_mfma_f32_16x16x32_bf16(af1, bf0, acc[1][0], 0, 0, 0);
            acc[1][1] = __builtin_amdgcn_mfma_f32_16x16x32_bf16(af1, bf1, acc[1][1], 0, 0, 0);
        }
    }
    #pragma unroll
    for (int fr = 0; fr < 2; ++fr) {
        #pragma unroll
        for (int fc = 0; fc < 2; ++fc) {
            int n = n0 + wc + fc * 16 + frow;
            float bv = bias[n];
            float lv = (MODE == 2) ? ls[n] : 0.f;
            #pragma unroll
            for (int rg = 0; rg < 4; ++rg) {
                int m = m0 + wr + fr * 16 + kg * 4 + rg;
                float vv = acc[fr][fc][rg] + bv;
                if (MODE == 1) vv = gelu_f(vv);
                if (MODE == 2) vv = res[(size_t)m * ldc + n] + lv * vv;
                C[(size_t)m * ldc + n] = vv;
            }
        }
    }
}

// ---------------- MFMA flash attention ----------------
// 1152 blocks x 128 threads. Block = one (b,h) x 32 q-rows (2 waves x 16 rows).
// XCD-swizzle: h = bid&7 so same-(b,h) q-tiles colocate per XCD L2.
// Double-buffered K/V chunks (64 keys) in LDS bf16; mask prefetched to regs.
__global__ __launch_bounds__(128) void attn_kernel(
    const float* __restrict__ q, const float* __restrict__ k,
    const float* __restrict__ v, const float* __restrict__ mask,
    float* __restrict__ ctx)
{
    const int bid = blockIdx.x;
    const int h = bid & 7;
    const int qt = (bid >> 3) % 9;
    const int b = (bid >> 3) / 9;
    const int q0 = qt * 32;
    const int t = threadIdx.x;
    const int w = t >> 6, l = t & 63;
    const int lr = l & 15, lg = l >> 4;
    constexpr int NC = (HW_ + 63) / 64;   // 13

    __shared__ unsigned short Ks[2][64][40];
    __shared__ unsigned short Vs[2][32][72];
    __shared__ unsigned short Pl[2][16][72];

    // Q A-frag: row=lr, k=lg*8+j
    bf16x8 qfrag;
    {
        const float* qrow = q + ((size_t)(b * NE_ + q0 + w * 16 + lr)) * D_ + h * DH_ + lg * 8;
        float4 qa = *(const float4*)(qrow);
        float4 qb4 = *(const float4*)(qrow + 4);
        U4H8 uq;
        uq.u = make_uint4(pack2bf(qa.x, qa.y), pack2bf(qa.z, qa.w),
                          pack2bf(qb4.x, qb4.y), pack2bf(qb4.z, qb4.w));
        qfrag = uq.h;
    }

    // staging assignment
    const int kkey = t >> 1, kdh = (t & 1) * 16;          // K: 1 key, 16 dh
    const int vdh = (t & 7) * 4, vk0 = (t >> 3) * 2;      // V: key pairs, 4 dh
    const float* kbase = k + ((size_t)b * HW_) * D_ + h * DH_;
    const float* vbase = v + ((size_t)b * HW_) * D_ + h * DH_;
    const float* mbase = mask + ((size_t)(b * H_ + h) * NE_ + q0 + w * 16 + lg * 4) * (size_t)HW_;

    float4 kreg[4], vreg[4];
    float mreg[4][4];   // [reg][fc]

    auto issue_kv = [&](int c0) {
        if (c0 + 64 <= HW_) {
            const float* kp = kbase + (size_t)(c0 + kkey) * D_ + kdh;
            kreg[0] = *(const float4*)(kp);     kreg[1] = *(const float4*)(kp + 4);
            kreg[2] = *(const float4*)(kp + 8); kreg[3] = *(const float4*)(kp + 12);
            #pragma unroll
            for (int r = 0; r < 2; ++r) {
                const float* vp = vbase + (size_t)(c0 + vk0 + 32 * r) * D_ + vdh;
                vreg[2 * r]     = *(const float4*)(vp);
                vreg[2 * r + 1] = *(const float4*)(vp + D_);
            }
        } else {
            float4 z = make_float4(0.f, 0.f, 0.f, 0.f);
            bool ok = (c0 + kkey) < HW_;
            if (ok) {
                const float* kp = kbase + (size_t)(c0 + kkey) * D_ + kdh;
                kreg[0] = *(const float4*)(kp);     kreg[1] = *(const float4*)(kp + 4);
                kreg[2] = *(const float4*)(kp + 8); kreg[3] = *(const float4*)(kp + 12);
            } else { kreg[0] = z; kreg[1] = z; kreg[2] = z; kreg[3] = z; }
            #pragma unroll
            for (int r = 0; r < 2; ++r) {
                int key = c0 + vk0 + 32 * r;
                const float* vp = vbase + (size_t)key * D_ + vdh;
                vreg[2 * r]     = (key < HW_)     ? *(const float4*)(vp)      : z;
                vreg[2 * r + 1] = (key + 1 < HW_) ? *(const float4*)(vp + D_) : z;
            }
        }
    };
    auto write_kv = [&](int bufi) {
        uint4 p0 = make_uint4(pack2bf(kreg[0].x, kreg[0].y), pack2bf(kreg[0].z, kreg[0].w),
                              pack2bf(kreg[1].x, kreg[1].y), pack2bf(kreg[1].z, kreg[1].w));
        uint4 p1 = make_uint4(pack2bf(kreg[2].x, kreg[2].y), pack2bf(kreg[2].z, kreg[2].w),
                              pack2bf(kreg[3].x, kreg[3].y), pack2bf(kreg[3].z, kreg[3].w));
        *(uint4*)&Ks[bufi][kkey][kdh]     = p0;
        *(uint4*)&Ks[bufi][kkey][kdh + 8] = p1;
        #pragma unroll
        for (int r = 0; r < 2; ++r) {
            const float* va = (const float*)&vreg[2 * r];
            const float* vb = (const float*)&vreg[2 * r + 1];
            #pragma unroll
            for (int i = 0; i < 4; ++i)
                *(unsigned*)&Vs[bufi][vdh + i][vk0 + 32 * r] = pack2bf(va[i], vb[i]);
        }
    };
    auto issue_mask = [&](int c0) {
        #pragma unroll
        for (int rg = 0; rg < 4; ++rg)
            #pragma unroll
            for (int fc = 0; fc < 4; ++fc) {
                int col = c0 + fc * 16 + lr;
                mreg[rg][fc] = (col < HW_) ? mbase[(size_t)rg * HW_ + col] : -1e30f;
            }
    };

    f32x4 oacc[2];
    oacc[0] = (f32x4){0.f, 0.f, 0.f, 0.f}; oacc[1] = oacc[0];
    float m_i[4] = {-INFINITY, -INFINITY, -INFINITY, -INFINITY};
    float l_i[4] = {0.f, 0.f, 0.f, 0.f};

    issue_kv(0);
    write_kv(0);
    issue_mask(0);
    __syncthreads();

    for (int c = 0; c < NC; ++c) {
        const int c0 = c * 64;
        const int cb = c & 1, nb = cb ^ 1;
        if (c + 1 < NC) issue_kv(c0 + 64);

        // QK^T: S[16 q, 64 keys]
        f32x4 sacc[4];
        #pragma unroll
        for (int fc = 0; fc < 4; ++fc) {
            sacc[fc] = (f32x4){0.f, 0.f, 0.f, 0.f};
            bf16x8 kf = *(const bf16x8*)&Ks[cb][fc * 16 + lr][lg * 8];
            sacc[fc] = __builtin_amdgcn_mfma_f32_16x16x32_bf16(qfrag, kf, sacc[fc], 0, 0, 0);
        }
        float s[4][4];   // [fc][reg]
        #pragma unroll
        for (int fc = 0; fc < 4; ++fc)
            #pragma unroll
            for (int rg = 0; rg < 4; ++rg)
                s[fc][rg] = sacc[fc][rg] * SCALE_ + mreg[rg][fc];
        if (c + 1 < NC) issue_mask(c0 + 64);

        // online softmax (rows = lg*4+rg, reduce across 16-lane group)
        float mloc[4];
        #pragma unroll
        for (int rg = 0; rg < 4; ++rg)
            mloc[rg] = fmaxf(fmaxf(s[0][rg], s[1][rg]), fmaxf(s[2][rg], s[3][rg]));
        #pragma unroll
        for (int off = 1; off < 16; off <<= 1)
            #pragma unroll
            for (int rg = 0; rg < 4; ++rg)
                mloc[rg] = fmaxf(mloc[rg], __shfl_xor(mloc[rg], off));
        float scl[4], lloc[4];
        #pragma unroll
        for (int rg = 0; rg < 4; ++rg) {
            float mn = fmaxf(m_i[rg], mloc[rg]);
            scl[rg] = __expf(m_i[rg] - mn);
            m_i[rg] = mn;
        }
        #pragma unroll
        for (int rg = 0; rg < 4; ++rg) {
            float acc = 0.f;
            #pragma unroll
            for (int fc = 0; fc < 4; ++fc) {
                float p = __expf(s[fc][rg] - m_i[rg]);
                s[fc][rg] = p;
                acc += p;
            }
            lloc[rg] = acc;
        }
        #pragma unroll
        for (int off = 1; off < 16; off <<= 1)
            #pragma unroll
            for (int rg = 0; rg < 4; ++rg)
                lloc[rg] += __shfl_xor(lloc[rg], off);
        #pragma unroll
        for (int rg = 0; rg < 4; ++rg) {
            l_i[rg] = l_i[rg] * scl[rg] + lloc[rg];
            oacc[0][rg] *= scl[rg];
            oacc[1][rg] *= scl[rg];
        }

        // P -> LDS (wave-private), then PV
        #pragma unroll
        for (int fc = 0; fc < 4; ++fc)
            #pragma unroll
            for (int rg = 0; rg < 4; ++rg)
                Pl[w][lg * 4 + rg][fc * 16 + lr] = f2bf(s[fc][rg]);
        #pragma unroll
        for (int ks2 = 0; ks2 < 2; ++ks2) {
            bf16x8 pf = *(const bf16x8*)&Pl[w][lr][ks2 * 32 + lg * 8];
            #pragma unroll
            for (int d2 = 0; d2 < 2; ++d2) {
                bf16x8 vf = *(const bf16x8*)&Vs[cb][d2 * 16 + lr][ks2 * 32 + lg * 8];
                oacc[d2] = __builtin_amdgcn_mfma_f32_16x16x32_bf16(pf, vf, oacc[d2], 0, 0, 0);
            }
        }

        if (c + 1 < NC) {
            write_kv(nb);
            __syncthreads();
        }
    }

    float* cbase = ctx + ((size_t)(b * NE_ + q0 + w * 16 + lg * 4)) * D_ + h * DH_;
    #pragma unroll
    for (int rg = 0; rg < 4; ++rg) {
        float inv = 1.0f / l_i[rg];
        #pragma unroll
        for (int d2 = 0; d2 < 2; ++d2)
            cbase[(size_t)rg * D_ + d2 * 16 + lr] = oacc[d2][rg] * inv;
    }
}

// ---------------- GAT kernels ----------------

__global__ void addenc_kernel(const float* __restrict__ ln, const float* __restrict__ node_enc,
                              const float* __restrict__ edge_enc,
                              float* __restrict__ nodes_f, float* __restrict__ edges_f) {
    int tid = blockIdx.x * 256 + threadIdx.x;   // B*NE*D
    int d = tid & 255;
    int row = tid >> 8;
    int b = row / NE_, pos = row % NE_;
    float v = ln[tid];
    if (pos < N_) {
        int rn = b * N_ + pos;
        nodes_f[(size_t)rn * D_ + d] = v + node_enc[(size_t)rn * D_ + d];
    } else {
        int re = b * E_ + (pos - N_);
        edges_f[(size_t)re * D_ + d] = v + edge_enc[(size_t)re * D_ + d];
    }
}

__global__ __launch_bounds__(256) void hidden_kernel(
    const float* __restrict__ gn1, const float* __restrict__ gn2,
    float* __restrict__ hid, const int* __restrict__ idx0,
    const float* __restrict__ attn_p_l, float* __restrict__ pres) {
    int e = blockIdx.x;
    int d = threadIdx.x;
    int n = idx0[e];
    float x = hid[(size_t)e * D_ + d] + gn1[(size_t)n * D_ + d] + gn2[(size_t)n * D_ + d];
    float hv = gelu_f(x);
    hid[(size_t)e * D_ + d] = hv;
    float pr = hv * attn_p_l[d];
    #pragma unroll
    for (int o = 1; o < 32; o <<= 1) pr += __shfl_xor(pr, o);
    if ((d & 31) == 0) pres[e * H_ + (d >> 5)] = pr;
}

__global__ void segsoft_kernel(const float* __restrict__ pres, const int* __restrict__ csr_off,
                               const int* __restrict__ csr_perm,
                               float* __restrict__ mseg, float* __restrict__ denom) {
    int tid = blockIdx.x * 256 + threadIdx.x;   // BN*H
    int n = tid >> 3, h = tid & 7;
    int s = csr_off[n], e2 = csr_off[n + 1];
    float mx = -INFINITY;
    for (int i = s; i < e2; ++i) mx = fmaxf(mx, pres[csr_perm[i] * H_ + h]);
    float sum = 0.f;
    for (int i = s; i < e2; ++i) sum += expf(pres[csr_perm[i] * H_ + h] - mx);
    mseg[tid] = mx;
    denom[tid] = sum;
}

__global__ void alpha_kernel(const float* __restrict__ pres, const int* __restrict__ idx0,
                             const float* __restrict__ mseg, const float* __restrict__ denom,
                             float* __restrict__ alpha) {
    int tid = blockIdx.x * 256 + threadIdx.x;   // BE*H
    int e = tid >> 3, h = tid & 7;
    int n = idx0[e];
    alpha[tid] = expf(pres[tid] - mseg[n * H_ + h]) / denom[n * H_ + h];
}

__global__ void vin_kernel(const float* __restrict__ nodes_f, const float* __restrict__ new_edges,
                           const int* __restrict__ idx1, float* __restrict__ vin) {
    int tid = blockIdx.x * 256 + threadIdx.x;   // BE*D
    int e = tid >> 8, d = tid & 255;
    vin[tid] = nodes_f[(size_t)idx1[e] * D_ + d] + new_edges[tid];
}

__global__ __launch_bounds__(256) void nodeagg_kernel(
    const float* __restrict__ vals, const float* __restrict__ alpha,
    const int* __restrict__ csr_off, const int* __restrict__ csr_perm,
    float* __restrict__ new_nodes) {
    int n = blockIdx.x;
    int d = threadIdx.x;
    int s = csr_off[n], e2 = csr_off[n + 1];
    int h = d >> 5;
    float acc = 0.f;
    for (int i = s; i < e2; ++i) {
        int e = csr_perm[i];
        acc += vals[(size_t)e * D_ + d] * alpha[e * H_ + h];
    }
    new_nodes[(size_t)n * D_ + d] = acc;
}

__global__ void gatres_kernel(float* __restrict__ ne, const float* __restrict__ new_nodes,
                              const float* __restrict__ new_edges, const float* __restrict__ ls2l) {
    int tid = blockIdx.x * 256 + threadIdx.x;   // B*NE*D
    int d = tid & 255;
    int row = tid >> 8;
    int b = row / NE_, pos = row % NE_;
    float g = (pos < N_) ? new_nodes[(size_t)(b * N_ + pos) * D_ + d]
                         : new_edges[(size_t)(b * E_ + (pos - N_)) * D_ + d];
    ne[tid] += ls2l[d] * g;
}

// ---------------- CSR build (deterministic) ----------------

__global__ void zero_counts(int* counts) {
    int t = blockIdx.x * 256 + threadIdx.x;
    if (t < BN_) counts[t] = 0;
}

__global__ void csr_count(const int* __restrict__ idx0, int* __restrict__ counts) {
    int e = blockIdx.x * 256 + threadIdx.x;
    if (e < BE_) atomicAdd(&counts[idx0[e]], 1);
}

__global__ __launch_bounds__(512) void csr_scan(const int* __restrict__ counts, int* __restrict__ csr_off) {
    __shared__ int buf[BN_];
    int t = threadIdx.x;
    int c = counts[t];
    buf[t] = c;
    __syncthreads();
    for (int o = 1; o < BN_; o <<= 1) {
        int add = (t >= o) ? buf[t - o] : 0;
        __syncthreads();
        buf[t] += add;
        __syncthreads();
    }
    csr_off[t] = buf[t] - c;
    if (t == BN_ - 1) csr_off[BN_] = buf[t];
}

__global__ __launch_bounds__(64) void csr_fill(const int* __restrict__ idx0,
                                               const int* __restrict__ csr_off,
                                               int* __restrict__ csr_perm) {
    int n = blockIdx.x;
    int lane = threadIdx.x;
    int w = csr_off[n];
    for (int c0 = 0; c0 < BE_; c0 += 64) {
        int e = c0 + lane;
        bool m = (idx0[e] == n);
        unsigned long long bal = __ballot(m);
        if (m) {
            int pre = __popcll(bal & ((1ull << lane) - 1ull));
            csr_perm[w + pre] = e;
        }
        w += __popcll(bal);
    }
}

// ---------------- host orchestration ----------------

static void launch_mgemm(hipStream_t s, int mode,
                         const float* A, int lda, const unsigned short* Bt,
                         const float* bias, const float* res, const float* ls,
                         float* C, int ldc, int M, int N, int K) {
    dim3 g(N / 64, M / 64);
    if (mode == 0)      mgemm_kernel<0><<<g, 256, 0, s>>>(A, lda, Bt, bias, res, ls, C, ldc, K);
    else if (mode == 1) mgemm_kernel<1><<<g, 256, 0, s>>>(A, lda, Bt, bias, res, ls, C, ldc, K);
    else                mgemm_kernel<2><<<g, 256, 0, s>>>(A, lda, Bt, bias, res, ls, C, ldc, K);
}

extern "C" void kernel_launch(void* const* d_in, const int* in_sizes, int n_in,
                              void* d_out, int out_size, void* d_ws, size_t ws_size,
                              hipStream_t stream) {
    const float* nodes    = (const float*)d_in[0];
    const float* edges    = (const float*)d_in[1];
    const float* images   = (const float*)d_in[2];
    const float* mask     = (const float*)d_in[3];
    const float* node_enc = (const float*)d_in[4];
    const float* edge_enc = (const float*)d_in[5];
    const float* ln1_g = (const float*)d_in[6];
    const float* ln1_b = (const float*)d_in[7];
    const float* Wqkv  = (const float*)d_in[8];
    const float* bqkv  = (const float*)d_in[9];
    const float* Wo    = (const float*)d_in[10];
    const float* bo    = (const float*)d_in[11];
    const float* ls1   = (const float*)d_in[12];
    const float* ln2_g = (const float*)d_in[13];
    const float* ln2_b = (const float*)d_in[14];
    const float* Wn1   = (const float*)d_in[15];
    const float* bn1   = (const float*)d_in[16];
    const float* Wn2   = (const float*)d_in[17];
    const float* bn2   = (const float*)d_in[18];
    const float* We    = (const float*)d_in[19];
    const float* be    = (const float*)d_in[20];
    const float* attn_p= (const float*)d_in[21];
    const float* Weo   = (const float*)d_in[22];
    const float* beo   = (const float*)d_in[23];
    const float* Wno   = (const float*)d_in[24];
    const float* bno   = (const float*)d_in[25];
    const float* ls2   = (const float*)d_in[26];
    const float* ln3_g = (const float*)d_in[27];
    const float* ln3_b = (const float*)d_in[28];
    const float* W1    = (const float*)d_in[29];
    const float* b1    = (const float*)d_in[30];
    const float* W2    = (const float*)d_in[31];
    const float* b2    = (const float*)d_in[32];
    const float* ls3   = (const float*)d_in[33];
    const int*   edge_index = (const int*)d_in[34];
    const int* idx0 = edge_index;
    const int* idx1 = edge_index + BE_;

    float* ne = (float*)d_out;   // d_out doubles as the running `ne` buffer

    float* cur = (float*)d_ws;
    auto alloc = [&](size_t nfl) { float* p = cur; cur += nfl; return p; };
    float* lnbuf    = alloc((size_t)B_ * NE_ * D_);
    float* qb       = alloc((size_t)B_ * NE_ * D_);
    float* kb       = alloc((size_t)B_ * HW_ * D_);
    float* vb       = alloc((size_t)B_ * HW_ * D_);
    float* ffnh     = kb;   // alias: k/v dead by FFN time
    float* ctxb     = alloc((size_t)B_ * NE_ * D_);
    float* nodes_f  = alloc((size_t)BN_ * D_);
    float* edges_f  = alloc((size_t)BE_ * D_);
    float* gn1      = alloc((size_t)BN_ * D_);
    float* gn2      = alloc((size_t)BN_ * D_);
    float* hid      = alloc((size_t)BE_ * D_);
    float* pres     = alloc((size_t)BE_ * H_);
    float* mseg     = alloc((size_t)BN_ * H_);
    float* denom    = alloc((size_t)BN_ * H_);
    float* alphab   = alloc((size_t)BE_ * H_);
    float* new_edges= alloc((size_t)BE_ * D_);
    float* vin      = alloc((size_t)BE_ * D_);
    float* valsb    = alloc((size_t)BE_ * D_);
    float* new_nodes= alloc((size_t)BN_ * D_);
    int* counts   = (int*)cur; cur += BN_;
    int* csr_off  = (int*)cur; cur += BN_ + 4;
    int* csr_perm = (int*)cur; cur += BE_;
    cur = (float*)(((uintptr_t)cur + 255) & ~(uintptr_t)255);
    unsigned short* wT = (unsigned short*)cur;   // 4 * LAYER_W bf16

    // ---- once-per-call preprocessing ----
    wtrans_kernel<<<4 * 1088, 256, 0, stream>>>(Wqkv, Wo, Wn1, Wn2, We, Weo, Wno, W1, W2, wT);
    zero_counts<<<2, 256, 0, stream>>>(counts);
    csr_count<<<BE_ / 256, 256, 0, stream>>>(idx0, counts);
    csr_scan<<<1, 512, 0, stream>>>(counts, csr_off);
    csr_fill<<<BN_, 64, 0, stream>>>(idx0, csr_off, csr_perm);
    concat_kernel<<<(B_ * NE_ * D_) / 256, 256, 0, stream>>>(nodes, edges, ne);

    for (int l = 0; l < L_; ++l) {
        const unsigned short* wTl = wT + (size_t)l * LAYER_W;
        const float* bqkv_l = bqkv + (size_t)l * 3 * D_;

        // ---- cross attention ----
        ln_kernel<<<B_ * NE_, 256, 0, stream>>>(ne, lnbuf, ln1_g + l * D_, ln1_b + l * D_);
        launch_mgemm(stream, 0, lnbuf, D_, wTl + OFF_Q, bqkv_l, nullptr, nullptr,
                     qb, D_, B_ * NE_, D_, D_);
        launch_mgemm(stream, 0, images, D_, wTl + OFF_K, bqkv_l + D_, nullptr, nullptr,
                     kb, D_, B_ * HW_, D_, D_);
        launch_mgemm(stream, 0, images, D_, wTl + OFF_V, bqkv_l + 2 * D_, nullptr, nullptr,
                     vb, D_, B_ * HW_, D_, D_);
        attn_kernel<<<1152, 128, 0, stream>>>(qb, kb, vb, mask, ctxb);
        launch_mgemm(stream, 2, ctxb, D_, wTl + OFF_WO, bo + l * D_, ne, ls1 + l * D_,
                     ne, D_, B_ * NE_, D_, D_);

        // ---- GAT ----
        ln_kernel<<<B_ * NE_, 256, 0, stream>>>(ne, lnbuf, ln2_g + l * D_, ln2_b + l * D_);
        addenc_kernel<<<(B_ * NE_ * D_) / 256, 256, 0, stream>>>(lnbuf, node_enc, edge_enc, nodes_f, edges_f);
        launch_mgemm(stream, 0, nodes_f, D_, wTl + OFF_WN1, bn1 + l * D_, nullptr, nullptr,
                     gn1, D_, BN_, D_, D_);
        launch_mgemm(stream, 0, nodes_f, D_, wTl + OFF_WN2, bn2 + l * D_, nullptr, nullptr,
                     gn2, D_, BN_, D_, D_);
        launch_mgemm(stream, 0, edges_f, D_, wTl + OFF_WE, be + l * D_, nullptr, nullptr,
                     hid, D_, BE_, D_, D_);
        hidden_kernel<<<BE_, 256, 0, stream>>>(gn1, gn2, hid, idx0, attn_p + (size_t)l * H_ * DH_, pres);
        segsoft_kernel<<<(BN_ * H_) / 256, 256, 0, stream>>>(pres, csr_off, csr_perm, mseg, denom);
        alpha_kernel<<<(BE_ * H_) / 256, 256, 0, stream>>>(pres, idx0, mseg, denom, alphab);
        launch_mgemm(stream, 0, hid, D_, wTl + OFF_WEO, beo + l * D_, nullptr, nullptr,
                     new_edges, D_, BE_, D_, D_);
        vin_kernel<<<(BE_ * D_) / 256, 256, 0, stream>>>(nodes_f, new_edges, idx1, vin);
        launch_mgemm(stream, 0, vin, D_, wTl + OFF_WNO, bno + l * D_, nullptr, nullptr,
                     valsb, D_, BE_, D_, D_);
        nodeagg_kernel<<<BN_, 256, 0, stream>>>(valsb, alphab, csr_off, csr_perm, new_nodes);
        gatres_kernel<<<(B_ * NE_ * D_) / 256, 256, 0, stream>>>(ne, new_nodes, new_edges, ls2 + l * D_);

        // ---- FFN ----
        ln_kernel<<<B_ * NE_, 256, 0, stream>>>(ne, lnbuf, ln3_g + l * D_, ln3_b + l * D_);
        launch_mgemm(stream, 1, lnbuf, D_, wTl + OFF_W1, b1 + l * FF_, nullptr, nullptr,
                     ffnh, FF_, B_ * NE_, FF_, D_);
        launch_mgemm(stream, 2, ffnh, FF_, wTl + OFF_W2, b2 + l * D_, ne, ls3 + l * D_,
                     ne, D_, B_ * NE_, D_, FF_);
    }
}

// Round 4
// 688.218 us; speedup vs baseline: 2.9270x; 1.2554x over previous
//
#include <hip/hip_runtime.h>
#include <math.h>

// ---- problem constants ----
static constexpr int B_  = 16;
static constexpr int N_  = 32;
static constexpr int E_  = 256;
static constexpr int D_  = 256;
static constexpr int H_  = 8;
static constexpr int HW_ = 784;
static constexpr int L_  = 4;
static constexpr int DH_ = 32;
static constexpr int FF_ = 1024;
static constexpr int BN_ = 512;
static constexpr int BE_ = 4096;
static constexpr int NE_ = 288;   // N+E
#define SCALE_ 0.17677669529663687f

// per-layer transposed-weight block (bf16 elems)
static constexpr size_t LAYER_W = 1114112;  // 9*65536 + 2*262144
static constexpr size_t OFF_Q   = 0;
static constexpr size_t OFF_K   = 65536;    // K then V contiguous -> fused N=512 GEMM
static constexpr size_t OFF_V   = 131072;
static constexpr size_t OFF_WO  = 196608;
static constexpr size_t OFF_WN1 = 262144;
static constexpr size_t OFF_WN2 = 327680;
static constexpr size_t OFF_WE  = 393216;
static constexpr size_t OFF_WEO = 458752;
static constexpr size_t OFF_WNO = 524288;
static constexpr size_t OFF_W1  = 589824;
static constexpr size_t OFF_W2  = 851968;

typedef __attribute__((ext_vector_type(8))) short bf16x8;
typedef __attribute__((ext_vector_type(4))) float f32x4;

__device__ __forceinline__ float gelu_f(float x) {
    return 0.5f * x * (1.0f + erff(x * 0.7071067811865476f));
}

__device__ __forceinline__ unsigned short f2bf(float x) {
    unsigned u = __float_as_uint(x);
    u += 0x7FFFu + ((u >> 16) & 1u);   // RNE
    return (unsigned short)(u >> 16);
}
__device__ __forceinline__ unsigned pack2bf(float a, float b) {
    return (unsigned)f2bf(a) | ((unsigned)f2bf(b) << 16);
}
__device__ __forceinline__ float bf2f(unsigned short u) {
    return __uint_as_float(((unsigned)u) << 16);
}

// ---------------- elementwise / LN kernels ----------------

__global__ void concat_kernel(const float* __restrict__ nodes, const float* __restrict__ edges,
                              float* __restrict__ ne) {
    int tid = blockIdx.x * 256 + threadIdx.x;   // B*NE*D
    int d = tid & 255;
    int row = tid >> 8;
    int b = row / NE_, pos = row % NE_;
    float v = (pos < N_) ? nodes[(size_t)(b * N_ + pos) * D_ + d]
                         : edges[(size_t)(b * E_ + (pos - N_)) * D_ + d];
    ne[tid] = v;
}

// images f32 -> bf16 (once per call)
__global__ void imgcast_kernel(const float* __restrict__ img, unsigned short* __restrict__ out) {
    int tid = blockIdx.x * 256 + threadIdx.x;   // (B*HW*D)/8 threads
    const float* p = img + (size_t)tid * 8;
    float4 a = *(const float4*)(p);
    float4 b = *(const float4*)(p + 4);
    uint4 o = make_uint4(pack2bf(a.x, a.y), pack2bf(a.z, a.w),
                         pack2bf(b.x, b.y), pack2bf(b.z, b.w));
    *(uint4*)&out[(size_t)tid * 8] = o;
}

__device__ __forceinline__ float ln_row_val(const float* __restrict__ x, int row, int d,
                                            const float* __restrict__ g, const float* __restrict__ bta,
                                            float* sh1, float* sh2) {
    float v = x[(size_t)row * D_ + d];
    float s = v, s2 = v * v;
    #pragma unroll
    for (int o = 32; o >= 1; o >>= 1) { s += __shfl_down(s, o); s2 += __shfl_down(s2, o); }
    int lane = d & 63, w = d >> 6;
    if (lane == 0) { sh1[w] = s; sh2[w] = s2; }
    __syncthreads();
    if (d == 0) {
        float a = sh1[0] + sh1[1] + sh1[2] + sh1[3];
        float c = sh2[0] + sh2[1] + sh2[2] + sh2[3];
        sh1[0] = a; sh2[0] = c;
    }
    __syncthreads();
    float mean = sh1[0] * (1.0f / D_);
    float var  = sh2[0] * (1.0f / D_) - mean * mean;
    float rstd = rsqrtf(var + 1e-5f);
    return (v - mean) * rstd * g[d] + bta[d];
}

// LN -> bf16 out
__global__ __launch_bounds__(256) void ln_kernel(const float* __restrict__ x,
                                                 unsigned short* __restrict__ y,
                                                 const float* __restrict__ g,
                                                 const float* __restrict__ bta) {
    __shared__ float sh1[4], sh2[4];
    const int row = blockIdx.x, d = threadIdx.x;
    float val = ln_row_val(x, row, d, g, bta, sh1, sh2);
    y[(size_t)row * D_ + d] = f2bf(val);
}

// LN2 fused with +enc and node/edge split, bf16 out
__global__ __launch_bounds__(256) void ln2enc_kernel(const float* __restrict__ x,
                                                     const float* __restrict__ g,
                                                     const float* __restrict__ bta,
                                                     const float* __restrict__ node_enc,
                                                     const float* __restrict__ edge_enc,
                                                     unsigned short* __restrict__ nodes_f,
                                                     unsigned short* __restrict__ edges_f) {
    __shared__ float sh1[4], sh2[4];
    const int row = blockIdx.x, d = threadIdx.x;
    float val = ln_row_val(x, row, d, g, bta, sh1, sh2);
    int b = row / NE_, pos = row % NE_;
    if (pos < N_) {
        int rn = b * N_ + pos;
        nodes_f[(size_t)rn * D_ + d] = f2bf(val + node_enc[(size_t)rn * D_ + d]);
    } else {
        int re = b * E_ + (pos - N_);
        edges_f[(size_t)re * D_ + d] = f2bf(val + edge_enc[(size_t)re * D_ + d]);
    }
}

// ---------------- weight transpose+cast: W[K,N] f32 -> Wt[N,K] bf16 ----------------
__global__ __launch_bounds__(256) void wtrans_kernel(
    const float* __restrict__ Wqkv, const float* __restrict__ Wo,
    const float* __restrict__ Wn1,  const float* __restrict__ Wn2,
    const float* __restrict__ We,   const float* __restrict__ Weo,
    const float* __restrict__ Wno,  const float* __restrict__ W1,
    const float* __restrict__ W2,   unsigned short* __restrict__ wT)
{
    const int bid = blockIdx.x;
    const int l = bid / 1088;
    int tl = bid % 1088;
    const float* src; int ld, K, Nn; unsigned short* dst;
    if (tl < 576) {
        int mid = tl >> 6; tl &= 63;
        K = 256; Nn = 256;
        if (mid < 3) {
            src = Wqkv + (size_t)l * 256 * 768 + mid * 256; ld = 768;
            dst = wT + (size_t)l * LAYER_W + (size_t)mid * 65536;
        } else {
            const float* bases[6] = {Wo, Wn1, Wn2, We, Weo, Wno};
            src = bases[mid - 3] + (size_t)l * 65536; ld = 256;
            dst = wT + (size_t)l * LAYER_W + OFF_WO + (size_t)(mid - 3) * 65536;
        }
    } else if (tl < 832) {
        tl -= 576; K = 256; Nn = 1024;
        src = W1 + (size_t)l * 262144; ld = 1024;
        dst = wT + (size_t)l * LAYER_W + OFF_W1;
    } else {
        tl -= 832; K = 1024; Nn = 256;
        src = W2 + (size_t)l * 262144; ld = 256;
        dst = wT + (size_t)l * LAYER_W + OFF_W2;
    }
    const int ntn = Nn >> 5;
    const int k0 = (tl / ntn) << 5, n0 = (tl % ntn) << 5;
    __shared__ float ts[32][33];
    const int t = threadIdx.x;
    const int kl = t >> 5, nl = t & 31;
    #pragma unroll
    for (int rr = 0; rr < 4; ++rr)
        ts[kl + rr * 8][nl] = src[(size_t)(k0 + kl + rr * 8) * ld + n0 + nl];
    __syncthreads();
    const int onl = t >> 3, okl = (t & 7) << 2;
    ushort4 o;
    o.x = f2bf(ts[okl + 0][onl]); o.y = f2bf(ts[okl + 1][onl]);
    o.z = f2bf(ts[okl + 2][onl]); o.w = f2bf(ts[okl + 3][onl]);
    *(ushort4*)&dst[(size_t)(n0 + onl) * K + k0 + okl] = o;
}

// ---------------- MFMA GEMM: C[M,N] = epi(A[M,K]_bf16 @ Bt[N,K]_bf16^T + bias) ----------------
// MODE 0: +bias ; MODE 1: gelu(+bias) ; MODE 2: res + ls*(+bias)
// OUTBF: 1 -> bf16 output, 0 -> f32 output
template<int MODE, int OUTBF>
__global__ __launch_bounds__(256) void mgemm_kernel(
    const unsigned short* __restrict__ A, int lda,
    const unsigned short* __restrict__ Bt,
    const float* __restrict__ bias,
    const float* __restrict__ res,
    const float* __restrict__ ls,
    void* __restrict__ Cv, int ldc, int K)
{
    __shared__ unsigned short As[64][72];
    __shared__ unsigned short Bs[64][72];
    const int m0 = blockIdx.y * 64, n0 = blockIdx.x * 64;
    const int t = threadIdx.x;
    const int l = t & 63, w = t >> 6;
    const int wr = (w >> 1) * 32, wc = (w & 1) * 32;
    const int srow = t >> 2, skc = (t & 3) * 16;
    const int frow = l & 15, kg = l >> 4;
    f32x4 acc[2][2];
    acc[0][0] = (f32x4){0.f,0.f,0.f,0.f}; acc[0][1] = acc[0][0];
    acc[1][0] = acc[0][0];                acc[1][1] = acc[0][0];
    for (int k0 = 0; k0 < K; k0 += 64) {
        const unsigned short* ap = A + (size_t)(m0 + srow) * lda + k0 + skc;
        uint4 aq0 = *(const uint4*)(ap);
        uint4 aq1 = *(const uint4*)(ap + 8);
        const unsigned short* bp = Bt + (size_t)(n0 + srow) * K + k0 + skc;
        uint4 bq0 = *(const uint4*)(bp);
        uint4 bq1 = *(const uint4*)(bp + 8);
        __syncthreads();
        *(uint4*)&As[srow][skc]     = aq0;
        *(uint4*)&As[srow][skc + 8] = aq1;
        *(uint4*)&Bs[srow][skc]     = bq0;
        *(uint4*)&Bs[srow][skc + 8] = bq1;
        __syncthreads();
        #pragma unroll
        for (int kk = 0; kk < 2; ++kk) {
            bf16x8 af0 = *(const bf16x8*)&As[wr + frow][kk * 32 + kg * 8];
            bf16x8 af1 = *(const bf16x8*)&As[wr + 16 + frow][kk * 32 + kg * 8];
            bf16x8 bf0 = *(const bf16x8*)&Bs[wc + frow][kk * 32 + kg * 8];
            bf16x8 bf1 = *(const bf16x8*)&Bs[wc + 16 + frow][kk * 32 + kg * 8];
            acc[0][0] = __builtin_amdgcn_mfma_f32_16x16x32_bf16(af0, bf0, acc[0][0], 0, 0, 0);
            acc[0][1] = __builtin_amdgcn_mfma_f32_16x16x32_bf16(af0, bf1, acc[0][1], 0, 0, 0);
            acc[1][0] = __builtin_amdgcn_mfma_f32_16x16x32_bf16(af1, bf0, acc[1][0], 0, 0, 0);
            acc[1][1] = __builtin_amdgcn_mfma_f32_16x16x32_bf16(af1, bf1, acc[1][1], 0, 0, 0);
        }
    }
    // C/D layout: col = lane&15, row = (lane>>4)*4 + reg
    #pragma unroll
    for (int fr = 0; fr < 2; ++fr) {
        #pragma unroll
        for (int fc = 0; fc < 2; ++fc) {
            int n = n0 + wc + fc * 16 + frow;
            float bv = bias[n];
            float lv = (MODE == 2) ? ls[n] : 0.f;
            #pragma unroll
            for (int rg = 0; rg < 4; ++rg) {
                int m = m0 + wr + fr * 16 + kg * 4 + rg;
                float vv = acc[fr][fc][rg] + bv;
                if (MODE == 1) vv = gelu_f(vv);
                if (MODE == 2) vv = res[(size_t)m * ldc + n] + lv * vv;
                if (OUTBF) ((unsigned short*)Cv)[(size_t)m * ldc + n] = f2bf(vv);
                else       ((float*)Cv)[(size_t)m * ldc + n] = vv;
            }
        }
    }
}

// ---------------- MFMA flash attention (bf16 Q / fused-KV inputs, bf16 ctx out) ----------------
// 1152 blocks x 128 threads. Block = one (b,h) x 32 q-rows (2 waves x 16 rows).
// kv layout: [B*HW][512] bf16, cols 0-255 = K, 256-511 = V (head h at h*32).
__global__ __launch_bounds__(128) void attn_kernel(
    const unsigned short* __restrict__ q, const unsigned short* __restrict__ kv,
    const float* __restrict__ mask, unsigned short* __restrict__ ctx)
{
    const int bid = blockIdx.x;
    const int h = bid & 7;
    const int qt = (bid >> 3) % 9;
    const int b = (bid >> 3) / 9;
    const int q0 = qt * 32;
    const int t = threadIdx.x;
    const int w = t >> 6, l = t & 63;
    const int lr = l & 15, lg = l >> 4;
    constexpr int NC = (HW_ + 63) / 64;   // 13

    __shared__ unsigned short Ks[2][64][40];
    __shared__ unsigned short Vs[2][32][72];
    __shared__ unsigned short Pl[2][16][72];

    // Q A-frag: row=lr, k=lg*8+j
    bf16x8 qfrag = *(const bf16x8*)(q + ((size_t)(b * NE_ + q0 + w * 16 + lr)) * D_ + h * DH_ + lg * 8);

    // staging assignment
    const int kkey = t >> 1, kdh = (t & 1) * 16;          // K: 1 key, 16 dh
    const int vdh = (t & 7) * 4, vk0 = (t >> 3) * 2;      // V: key pairs, 4 dh
    const unsigned short* kbase = kv + ((size_t)b * HW_) * 512 + h * DH_;
    const unsigned short* vbase = kv + ((size_t)b * HW_) * 512 + 256 + h * DH_;
    const float* mbase = mask + ((size_t)(b * H_ + h) * NE_ + q0 + w * 16 + lg * 4) * (size_t)HW_;

    uint4 kq0, kq1;
    ushort4 va[2], vb4[2];
    float mreg[4][4];   // [reg][fc]

    auto issue_kv = [&](int c0) {
        {
            int key = c0 + kkey;
            bool ok = key < HW_;
            const unsigned short* kp = kbase + (size_t)(ok ? key : 0) * 512 + kdh;
            kq0 = *(const uint4*)(kp);
            kq1 = *(const uint4*)(kp + 8);
            if (!ok) { kq0 = make_uint4(0,0,0,0); kq1 = kq0; }
        }
        #pragma unroll
        for (int r = 0; r < 2; ++r) {
            int key = c0 + vk0 + 32 * r;
            bool ok0 = key < HW_, ok1 = (key + 1) < HW_;
            const unsigned short* vp = vbase + (size_t)(ok0 ? key : 0) * 512 + vdh;
            va[r]  = *(const ushort4*)(vp);
            vb4[r] = *(const ushort4*)(vp + (ok1 ? 512 : 0));
            if (!ok0) va[r]  = make_ushort4(0,0,0,0);
            if (!ok1) vb4[r] = make_ushort4(0,0,0,0);
        }
    };
    auto write_kv = [&](int bufi) {
        *(uint4*)&Ks[bufi][kkey][kdh]     = kq0;
        *(uint4*)&Ks[bufi][kkey][kdh + 8] = kq1;
        #pragma unroll
        for (int r = 0; r < 2; ++r) {
            const unsigned short* a = (const unsigned short*)&va[r];
            const unsigned short* c = (const unsigned short*)&vb4[r];
            #pragma unroll
            for (int i = 0; i < 4; ++i)
                *(unsigned*)&Vs[bufi][vdh + i][vk0 + 32 * r] = (unsigned)a[i] | ((unsigned)c[i] << 16);
        }
    };
    auto issue_mask = [&](int c0) {
        #pragma unroll
        for (int rg = 0; rg < 4; ++rg)
            #pragma unroll
            for (int fc = 0; fc < 4; ++fc) {
                int col = c0 + fc * 16 + lr;
                mreg[rg][fc] = (col < HW_) ? mbase[(size_t)rg * HW_ + col] : -1e30f;
            }
    };

    f32x4 oacc[2];
    oacc[0] = (f32x4){0.f, 0.f, 0.f, 0.f}; oacc[1] = oacc[0];
    float m_i[4] = {-INFINITY, -INFINITY, -INFINITY, -INFINITY};
    float l_i[4] = {0.f, 0.f, 0.f, 0.f};

    issue_kv(0);
    write_kv(0);
    issue_mask(0);
    __syncthreads();

    for (int c = 0; c < NC; ++c) {
        const int c0 = c * 64;
        const int cb = c & 1, nb = cb ^ 1;
        if (c + 1 < NC) issue_kv(c0 + 64);

        // QK^T: S[16 q, 64 keys]
        f32x4 sacc[4];
        #pragma unroll
        for (int fc = 0; fc < 4; ++fc) {
            sacc[fc] = (f32x4){0.f, 0.f, 0.f, 0.f};
            bf16x8 kf = *(const bf16x8*)&Ks[cb][fc * 16 + lr][lg * 8];
            sacc[fc] = __builtin_amdgcn_mfma_f32_16x16x32_bf16(qfrag, kf, sacc[fc], 0, 0, 0);
        }
        float s[4][4];   // [fc][reg]
        #pragma unroll
        for (int fc = 0; fc < 4; ++fc)
            #pragma unroll
            for (int rg = 0; rg < 4; ++rg)
                s[fc][rg] = sacc[fc][rg] * SCALE_ + mreg[rg][fc];
        if (c + 1 < NC) issue_mask(c0 + 64);

        // online softmax (rows = lg*4+rg, reduce across 16-lane group)
        float mloc[4];
        #pragma unroll
        for (int rg = 0; rg < 4; ++rg)
            mloc[rg] = fmaxf(fmaxf(s[0][rg], s[1][rg]), fmaxf(s[2][rg], s[3][rg]));
        #pragma unroll
        for (int off = 1; off < 16; off <<= 1)
            #pragma unroll
            for (int rg = 0; rg < 4; ++rg)
                mloc[rg] = fmaxf(mloc[rg], __shfl_xor(mloc[rg], off));
        float scl[4], lloc[4];
        #pragma unroll
        for (int rg = 0; rg < 4; ++rg) {
            float mn = fmaxf(m_i[rg], mloc[rg]);
            scl[rg] = __expf(m_i[rg] - mn);
            m_i[rg] = mn;
        }
        #pragma unroll
        for (int rg = 0; rg < 4; ++rg) {
            float acc = 0.f;
            #pragma unroll
            for (int fc = 0; fc < 4; ++fc) {
                float p = __expf(s[fc][rg] - m_i[rg]);
                s[fc][rg] = p;
                acc += p;
            }
            lloc[rg] = acc;
        }
        #pragma unroll
        for (int off = 1; off < 16; off <<= 1)
            #pragma unroll
            for (int rg = 0; rg < 4; ++rg)
                lloc[rg] += __shfl_xor(lloc[rg], off);
        #pragma unroll
        for (int rg = 0; rg < 4; ++rg) {
            l_i[rg] = l_i[rg] * scl[rg] + lloc[rg];
            oacc[0][rg] *= scl[rg];
            oacc[1][rg] *= scl[rg];
        }

        // P -> LDS (wave-private), then PV
        #pragma unroll
        for (int fc = 0; fc < 4; ++fc)
            #pragma unroll
            for (int rg = 0; rg < 4; ++rg)
                Pl[w][lg * 4 + rg][fc * 16 + lr] = f2bf(s[fc][rg]);
        #pragma unroll
        for (int ks2 = 0; ks2 < 2; ++ks2) {
            bf16x8 pf = *(const bf16x8*)&Pl[w][lr][ks2 * 32 + lg * 8];
            #pragma unroll
            for (int d2 = 0; d2 < 2; ++d2) {
                bf16x8 vf = *(const bf16x8*)&Vs[cb][d2 * 16 + lr][ks2 * 32 + lg * 8];
                oacc[d2] = __builtin_amdgcn_mfma_f32_16x16x32_bf16(pf, vf, oacc[d2], 0, 0, 0);
            }
        }

        if (c + 1 < NC) {
            write_kv(nb);
            __syncthreads();
        }
    }

    unsigned short* cbase = ctx + ((size_t)(b * NE_ + q0 + w * 16 + lg * 4)) * D_ + h * DH_;
    #pragma unroll
    for (int rg = 0; rg < 4; ++rg) {
        float inv = 1.0f / l_i[rg];
        #pragma unroll
        for (int d2 = 0; d2 < 2; ++d2)
            cbase[(size_t)rg * D_ + d2 * 16 + lr] = f2bf(oacc[d2][rg] * inv);
    }
}

// ---------------- GAT kernels ----------------

// hid holds ep (bf16) on entry; out: hid = gelu(gn1[idx0]+gn2[idx0]+ep) bf16, pres[e][h]
__global__ __launch_bounds__(256) void hidden_kernel(
    const float* __restrict__ gn1, const float* __restrict__ gn2,
    unsigned short* __restrict__ hid, const int* __restrict__ idx0,
    const float* __restrict__ attn_p_l, float* __restrict__ pres) {
    int e = blockIdx.x;
    int d = threadIdx.x;
    int n = idx0[e];
    float x = bf2f(hid[(size_t)e * D_ + d]) + gn1[(size_t)n * D_ + d] + gn2[(size_t)n * D_ + d];
    float hv = gelu_f(x);
    hid[(size_t)e * D_ + d] = f2bf(hv);
    float pr = hv * attn_p_l[d];
    #pragma unroll
    for (int o = 1; o < 32; o <<= 1) pr += __shfl_xor(pr, o);
    if ((d & 31) == 0) pres[e * H_ + (d >> 5)] = pr;
}

__global__ void segsoft_kernel(const float* __restrict__ pres, const int* __restrict__ csr_off,
                               const int* __restrict__ csr_perm,
                               float* __restrict__ mseg, float* __restrict__ denom) {
    int tid = blockIdx.x * 256 + threadIdx.x;   // BN*H
    int n = tid >> 3, h = tid & 7;
    int s = csr_off[n], e2 = csr_off[n + 1];
    float mx = -INFINITY;
    for (int i = s; i < e2; ++i) mx = fmaxf(mx, pres[csr_perm[i] * H_ + h]);
    float sum = 0.f;
    for (int i = s; i < e2; ++i) sum += expf(pres[csr_perm[i] * H_ + h] - mx);
    mseg[tid] = mx;
    denom[tid] = sum;
}

__global__ void alpha_kernel(const float* __restrict__ pres, const int* __restrict__ idx0,
                             const float* __restrict__ mseg, const float* __restrict__ denom,
                             float* __restrict__ alpha) {
    int tid = blockIdx.x * 256 + threadIdx.x;   // BE*H
    int e = tid >> 3, h = tid & 7;
    int n = idx0[e];
    alpha[tid] = expf(pres[tid] - mseg[n * H_ + h]) / denom[n * H_ + h];
}

__global__ void vin_kernel(const unsigned short* __restrict__ nodes_f,
                           const float* __restrict__ new_edges,
                           const int* __restrict__ idx1, unsigned short* __restrict__ vin) {
    int tid = blockIdx.x * 256 + threadIdx.x;   // BE*D
    int e = tid >> 8, d = tid & 255;
    vin[tid] = f2bf(bf2f(nodes_f[(size_t)idx1[e] * D_ + d]) + new_edges[tid]);
}

__global__ __launch_bounds__(256) void nodeagg_kernel(
    const float* __restrict__ vals, const float* __restrict__ alpha,
    const int* __restrict__ csr_off, const int* __restrict__ csr_perm,
    float* __restrict__ new_nodes) {
    int n = blockIdx.x;
    int d = threadIdx.x;
    int s = csr_off[n], e2 = csr_off[n + 1];
    int h = d >> 5;
    float acc = 0.f;
    for (int i = s; i < e2; ++i) {
        int e = csr_perm[i];
        acc += vals[(size_t)e * D_ + d] * alpha[e * H_ + h];
    }
    new_nodes[(size_t)n * D_ + d] = acc;
}

__global__ void gatres_kernel(float* __restrict__ ne, const float* __restrict__ new_nodes,
                              const float* __restrict__ new_edges, const float* __restrict__ ls2l) {
    int tid = blockIdx.x * 256 + threadIdx.x;   // B*NE*D
    int d = tid & 255;
    int row = tid >> 8;
    int b = row / NE_, pos = row % NE_;
    float g = (pos < N_) ? new_nodes[(size_t)(b * N_ + pos) * D_ + d]
                         : new_edges[(size_t)(b * E_ + (pos - N_)) * D_ + d];
    ne[tid] += ls2l[d] * g;
}

// ---------------- CSR build (deterministic) ----------------

__global__ void zero_counts(int* counts) {
    int t = blockIdx.x * 256 + threadIdx.x;
    if (t < BN_) counts[t] = 0;
}

__global__ void csr_count(const int* __restrict__ idx0, int* __restrict__ counts) {
    int e = blockIdx.x * 256 + threadIdx.x;
    if (e < BE_) atomicAdd(&counts[idx0[e]], 1);
}

__global__ __launch_bounds__(512) void csr_scan(const int* __restrict__ counts, int* __restrict__ csr_off) {
    __shared__ int buf[BN_];
    int t = threadIdx.x;
    int c = counts[t];
    buf[t] = c;
    __syncthreads();
    for (int o = 1; o < BN_; o <<= 1) {
        int add = (t >= o) ? buf[t - o] : 0;
        __syncthreads();
        buf[t] += add;
        __syncthreads();
    }
    csr_off[t] = buf[t] - c;
    if (t == BN_ - 1) csr_off[BN_] = buf[t];
}

__global__ __launch_bounds__(64) void csr_fill(const int* __restrict__ idx0,
                                               const int* __restrict__ csr_off,
                                               int* __restrict__ csr_perm) {
    int n = blockIdx.x;
    int lane = threadIdx.x;
    int w = csr_off[n];
    for (int c0 = 0; c0 < BE_; c0 += 64) {
        int e = c0 + lane;
        bool m = (idx0[e] == n);
        unsigned long long bal = __ballot(m);
        if (m) {
            int pre = __popcll(bal & ((1ull << lane) - 1ull));
            csr_perm[w + pre] = e;
        }
        w += __popcll(bal);
    }
}

// ---------------- host orchestration ----------------

static void launch_mgemm(hipStream_t s, int mode, int outbf,
                         const unsigned short* A, int lda, const unsigned short* Bt,
                         const float* bias, const float* res, const float* ls,
                         void* C, int ldc, int M, int N, int K) {
    dim3 g(N / 64, M / 64);
    if (mode == 0) {
        if (outbf) mgemm_kernel<0,1><<<g, 256, 0, s>>>(A, lda, Bt, bias, res, ls, C, ldc, K);
        else       mgemm_kernel<0,0><<<g, 256, 0, s>>>(A, lda, Bt, bias, res, ls, C, ldc, K);
    } else if (mode == 1) {
        mgemm_kernel<1,1><<<g, 256, 0, s>>>(A, lda, Bt, bias, res, ls, C, ldc, K);
    } else {
        mgemm_kernel<2,0><<<g, 256, 0, s>>>(A, lda, Bt, bias, res, ls, C, ldc, K);
    }
}

extern "C" void kernel_launch(void* const* d_in, const int* in_sizes, int n_in,
                              void* d_out, int out_size, void* d_ws, size_t ws_size,
                              hipStream_t stream) {
    const float* nodes    = (const float*)d_in[0];
    const float* edges    = (const float*)d_in[1];
    const float* images   = (const float*)d_in[2];
    const float* mask     = (const float*)d_in[3];
    const float* node_enc = (const float*)d_in[4];
    const float* edge_enc = (const float*)d_in[5];
    const float* ln1_g = (const float*)d_in[6];
    const float* ln1_b = (const float*)d_in[7];
    const float* Wqkv  = (const float*)d_in[8];
    const float* bqkv  = (const float*)d_in[9];
    const float* Wo    = (const float*)d_in[10];
    const float* bo    = (const float*)d_in[11];
    const float* ls1   = (const float*)d_in[12];
    const float* ln2_g = (const float*)d_in[13];
    const float* ln2_b = (const float*)d_in[14];
    const float* Wn1   = (const float*)d_in[15];
    const float* bn1   = (const float*)d_in[16];
    const float* Wn2   = (const float*)d_in[17];
    const float* bn2   = (const float*)d_in[18];
    const float* We    = (const float*)d_in[19];
    const float* be    = (const float*)d_in[20];
    const float* attn_p= (const float*)d_in[21];
    const float* Weo   = (const float*)d_in[22];
    const float* beo   = (const float*)d_in[23];
    const float* Wno   = (const float*)d_in[24];
    const float* bno   = (const float*)d_in[25];
    const float* ls2   = (const float*)d_in[26];
    const float* ln3_g = (const float*)d_in[27];
    const float* ln3_b = (const float*)d_in[28];
    const float* W1    = (const float*)d_in[29];
    const float* b1    = (const float*)d_in[30];
    const float* W2    = (const float*)d_in[31];
    const float* b2    = (const float*)d_in[32];
    const float* ls3   = (const float*)d_in[33];
    const int*   edge_index = (const int*)d_in[34];
    const int* idx0 = edge_index;
    const int* idx1 = edge_index + BE_;

    float* ne = (float*)d_out;   // d_out doubles as the running `ne` buffer

    float* cur = (float*)d_ws;
    auto alloc = [&](size_t nfl) { float* p = cur; cur += nfl; return p; };
    auto allocbf = [&](size_t nbf) { float* p = cur; cur += (nbf + 1) / 2; return (unsigned short*)p; };

    unsigned short* lnbuf   = allocbf((size_t)B_ * NE_ * D_);
    unsigned short* qb      = allocbf((size_t)B_ * NE_ * D_);
    unsigned short* kvb     = allocbf((size_t)B_ * HW_ * 512);     // K|V fused, ld=512
    unsigned short* imgbf   = allocbf((size_t)B_ * HW_ * D_);
    unsigned short* ctxb    = allocbf((size_t)B_ * NE_ * D_);
    unsigned short* ffnh    = allocbf((size_t)B_ * NE_ * FF_);
    unsigned short* nodes_f = allocbf((size_t)BN_ * D_);
    unsigned short* edges_f = allocbf((size_t)BE_ * D_);
    unsigned short* hid     = allocbf((size_t)BE_ * D_);
    unsigned short* vin     = allocbf((size_t)BE_ * D_);
    float* gn1      = alloc((size_t)BN_ * D_);
    float* gn2      = alloc((size_t)BN_ * D_);
    float* pres     = alloc((size_t)BE_ * H_);
    float* mseg     = alloc((size_t)BN_ * H_);
    float* denom    = alloc((size_t)BN_ * H_);
    float* alphab   = alloc((size_t)BE_ * H_);
    float* new_edges= alloc((size_t)BE_ * D_);
    float* valsb    = alloc((size_t)BE_ * D_);
    float* new_nodes= alloc((size_t)BN_ * D_);
    int* counts   = (int*)cur; cur += BN_;
    int* csr_off  = (int*)cur; cur += BN_ + 4;
    int* csr_perm = (int*)cur; cur += BE_;
    cur = (float*)(((uintptr_t)cur + 255) & ~(uintptr_t)255);
    unsigned short* wT = (unsigned short*)cur;   // 4 * LAYER_W bf16

    // ---- once-per-call preprocessing ----
    wtrans_kernel<<<4 * 1088, 256, 0, stream>>>(Wqkv, Wo, Wn1, Wn2, We, Weo, Wno, W1, W2, wT);
    imgcast_kernel<<<(B_ * HW_ * D_) / (256 * 8), 256, 0, stream>>>(images, imgbf);
    zero_counts<<<2, 256, 0, stream>>>(counts);
    csr_count<<<BE_ / 256, 256, 0, stream>>>(idx0, counts);
    csr_scan<<<1, 512, 0, stream>>>(counts, csr_off);
    csr_fill<<<BN_, 64, 0, stream>>>(idx0, csr_off, csr_perm);
    concat_kernel<<<(B_ * NE_ * D_) / 256, 256, 0, stream>>>(nodes, edges, ne);

    for (int l = 0; l < L_; ++l) {
        const unsigned short* wTl = wT + (size_t)l * LAYER_W;
        const float* bqkv_l = bqkv + (size_t)l * 3 * D_;

        // ---- cross attention ----
        ln_kernel<<<B_ * NE_, 256, 0, stream>>>(ne, lnbuf, ln1_g + l * D_, ln1_b + l * D_);
        launch_mgemm(stream, 0, 1, lnbuf, D_, wTl + OFF_Q, bqkv_l, nullptr, nullptr,
                     qb, D_, B_ * NE_, D_, D_);
        // fused K|V projection: N=512 (Wk^T and Wv^T contiguous in wT)
        launch_mgemm(stream, 0, 1, imgbf, D_, wTl + OFF_K, bqkv_l + D_, nullptr, nullptr,
                     kvb, 512, B_ * HW_, 512, D_);
        attn_kernel<<<1152, 128, 0, stream>>>(qb, kvb, mask, ctxb);
        launch_mgemm(stream, 2, 0, ctxb, D_, wTl + OFF_WO, bo + l * D_, ne, ls1 + l * D_,
                     ne, D_, B_ * NE_, D_, D_);

        // ---- GAT ----
        ln2enc_kernel<<<B_ * NE_, 256, 0, stream>>>(ne, ln2_g + l * D_, ln2_b + l * D_,
                                                    node_enc, edge_enc, nodes_f, edges_f);
        launch_mgemm(stream, 0, 0, nodes_f, D_, wTl + OFF_WN1, bn1 + l * D_, nullptr, nullptr,
                     gn1, D_, BN_, D_, D_);
        launch_mgemm(stream, 0, 0, nodes_f, D_, wTl + OFF_WN2, bn2 + l * D_, nullptr, nullptr,
                     gn2, D_, BN_, D_, D_);
        launch_mgemm(stream, 0, 1, edges_f, D_, wTl + OFF_WE, be + l * D_, nullptr, nullptr,
                     hid, D_, BE_, D_, D_);
        hidden_kernel<<<BE_, 256, 0, stream>>>(gn1, gn2, hid, idx0, attn_p + (size_t)l * H_ * DH_, pres);
        segsoft_kernel<<<(BN_ * H_) / 256, 256, 0, stream>>>(pres, csr_off, csr_perm, mseg, denom);
        alpha_kernel<<<(BE_ * H_) / 256, 256, 0, stream>>>(pres, idx0, mseg, denom, alphab);
        launch_mgemm(stream, 0, 0, hid, D_, wTl + OFF_WEO, beo + l * D_, nullptr, nullptr,
                     new_edges, D_, BE_, D_, D_);
        vin_kernel<<<(BE_ * D_) / 256, 256, 0, stream>>>(nodes_f, new_edges, idx1, vin);
        launch_mgemm(stream, 0, 0, vin, D_, wTl + OFF_WNO, bno + l * D_, nullptr, nullptr,
                     valsb, D_, BE_, D_, D_);
        nodeagg_kernel<<<BN_, 256, 0, stream>>>(valsb, alphab, csr_off, csr_perm, new_nodes);
        gatres_kernel<<<(B_ * NE_ * D_) / 256, 256, 0, stream>>>(ne, new_nodes, new_edges, ls2 + l * D_);

        // ---- FFN ----
        ln_kernel<<<B_ * NE_, 256, 0, stream>>>(ne, lnbuf, ln3_g + l * D_, ln3_b + l * D_);
        launch_mgemm(stream, 1, 1, lnbuf, D_, wTl + OFF_W1, b1 + l * FF_, nullptr, nullptr,
                     ffnh, FF_, B_ * NE_, FF_, D_);
        launch_mgemm(stream, 2, 0, ffnh, FF_, wTl + OFF_W2, b2 + l * D_, ne, ls3 + l * D_,
                     ne, D_, B_ * NE_, D_, FF_);
    }
}

// Round 5
// 675.777 us; speedup vs baseline: 2.9809x; 1.0184x over previous
//
#include <hip/hip_runtime.h>
#include <math.h>

// ---- problem constants ----
static constexpr int B_  = 16;
static constexpr int N_  = 32;
static constexpr int E_  = 256;
static constexpr int D_  = 256;
static constexpr int H_  = 8;
static constexpr int HW_ = 784;
static constexpr int L_  = 4;
static constexpr int DH_ = 32;
static constexpr int FF_ = 1024;
static constexpr int BN_ = 512;
static constexpr int BE_ = 4096;
static constexpr int NE_ = 288;   // N+E
#define SCALE_ 0.17677669529663687f

// per-layer transposed-weight block (bf16 elems)
static constexpr size_t LAYER_W = 1114112;  // 9*65536 + 2*262144
static constexpr size_t OFF_Q   = 0;
static constexpr size_t OFF_K   = 65536;    // K then V contiguous -> fused N=512 GEMM
static constexpr size_t OFF_WO  = 196608;
static constexpr size_t OFF_WN1 = 262144;   // WN1 then WN2 contiguous -> fused N=512 GEMM
static constexpr size_t OFF_WE  = 393216;
static constexpr size_t OFF_WEO = 458752;
static constexpr size_t OFF_WNO = 524288;
static constexpr size_t OFF_W1  = 589824;
static constexpr size_t OFF_W2  = 851968;

typedef __attribute__((ext_vector_type(8))) short bf16x8;
typedef __attribute__((ext_vector_type(4))) float f32x4;

__device__ __forceinline__ float gelu_f(float x) {
    return 0.5f * x * (1.0f + erff(x * 0.7071067811865476f));
}

__device__ __forceinline__ unsigned short f2bf(float x) {
    unsigned u = __float_as_uint(x);
    u += 0x7FFFu + ((u >> 16) & 1u);   // RNE
    return (unsigned short)(u >> 16);
}
__device__ __forceinline__ unsigned pack2bf(float a, float b) {
    return (unsigned)f2bf(a) | ((unsigned)f2bf(b) << 16);
}
__device__ __forceinline__ float bf2f(unsigned short u) {
    return __uint_as_float(((unsigned)u) << 16);
}

// ---------------- elementwise / LN kernels ----------------

__global__ void concat_kernel(const float* __restrict__ nodes, const float* __restrict__ edges,
                              float* __restrict__ ne) {
    int tid = blockIdx.x * 256 + threadIdx.x;   // B*NE*D
    int d = tid & 255;
    int row = tid >> 8;
    int b = row / NE_, pos = row % NE_;
    float v = (pos < N_) ? nodes[(size_t)(b * N_ + pos) * D_ + d]
                         : edges[(size_t)(b * E_ + (pos - N_)) * D_ + d];
    ne[tid] = v;
}

// images f32 -> bf16 (once per call)
__global__ void imgcast_kernel(const float* __restrict__ img, unsigned short* __restrict__ out) {
    int tid = blockIdx.x * 256 + threadIdx.x;   // (B*HW*D)/8 threads
    const float* p = img + (size_t)tid * 8;
    float4 a = *(const float4*)(p);
    float4 b = *(const float4*)(p + 4);
    uint4 o = make_uint4(pack2bf(a.x, a.y), pack2bf(a.z, a.w),
                         pack2bf(b.x, b.y), pack2bf(b.z, b.w));
    *(uint4*)&out[(size_t)tid * 8] = o;
}

// LN core given the row value already in-register
__device__ __forceinline__ float ln_from_val(float v, int d,
                                             const float* __restrict__ g, const float* __restrict__ bta,
                                             float* sh1, float* sh2) {
    float s = v, s2 = v * v;
    #pragma unroll
    for (int o = 32; o >= 1; o >>= 1) { s += __shfl_down(s, o); s2 += __shfl_down(s2, o); }
    int lane = d & 63, w = d >> 6;
    if (lane == 0) { sh1[w] = s; sh2[w] = s2; }
    __syncthreads();
    if (d == 0) {
        float a = sh1[0] + sh1[1] + sh1[2] + sh1[3];
        float c = sh2[0] + sh2[1] + sh2[2] + sh2[3];
        sh1[0] = a; sh2[0] = c;
    }
    __syncthreads();
    float mean = sh1[0] * (1.0f / D_);
    float var  = sh2[0] * (1.0f / D_) - mean * mean;
    float rstd = rsqrtf(var + 1e-5f);
    return (v - mean) * rstd * g[d] + bta[d];
}

// LN -> bf16 out
__global__ __launch_bounds__(256) void ln_kernel(const float* __restrict__ x,
                                                 unsigned short* __restrict__ y,
                                                 const float* __restrict__ g,
                                                 const float* __restrict__ bta) {
    __shared__ float sh1[4], sh2[4];
    const int row = blockIdx.x, d = threadIdx.x;
    float v = x[(size_t)row * D_ + d];
    y[(size_t)row * D_ + d] = f2bf(ln_from_val(v, d, g, bta, sh1, sh2));
}

// LN2 fused with +enc and node/edge split, bf16 out
__global__ __launch_bounds__(256) void ln2enc_kernel(const float* __restrict__ x,
                                                     const float* __restrict__ g,
                                                     const float* __restrict__ bta,
                                                     const float* __restrict__ node_enc,
                                                     const float* __restrict__ edge_enc,
                                                     unsigned short* __restrict__ nodes_f,
                                                     unsigned short* __restrict__ edges_f) {
    __shared__ float sh1[4], sh2[4];
    const int row = blockIdx.x, d = threadIdx.x;
    float v = x[(size_t)row * D_ + d];
    float val = ln_from_val(v, d, g, bta, sh1, sh2);
    int b = row / NE_, pos = row % NE_;
    if (pos < N_) {
        int rn = b * N_ + pos;
        nodes_f[(size_t)rn * D_ + d] = f2bf(val + node_enc[(size_t)rn * D_ + d]);
    } else {
        int re = b * E_ + (pos - N_);
        edges_f[(size_t)re * D_ + d] = f2bf(val + edge_enc[(size_t)re * D_ + d]);
    }
}

// gat residual + LN3 fused: ne2 = ne + ls2*gat (write ne), lnbuf = LN(ne2) bf16
__global__ __launch_bounds__(256) void gatres_ln_kernel(
    float* __restrict__ ne, const float* __restrict__ new_nodes,
    const float* __restrict__ new_edges, const float* __restrict__ ls2l,
    const float* __restrict__ g, const float* __restrict__ bta,
    unsigned short* __restrict__ lnb) {
    __shared__ float sh1[4], sh2[4];
    const int row = blockIdx.x, d = threadIdx.x;
    int b = row / NE_, pos = row % NE_;
    float gv = (pos < N_) ? new_nodes[(size_t)(b * N_ + pos) * D_ + d]
                          : new_edges[(size_t)(b * E_ + (pos - N_)) * D_ + d];
    float v = ne[(size_t)row * D_ + d] + ls2l[d] * gv;
    ne[(size_t)row * D_ + d] = v;
    lnb[(size_t)row * D_ + d] = f2bf(ln_from_val(v, d, g, bta, sh1, sh2));
}

// ---------------- weight transpose+cast: W[K,N] f32 -> Wt[N,K] bf16 ----------------
__global__ __launch_bounds__(256) void wtrans_kernel(
    const float* __restrict__ Wqkv, const float* __restrict__ Wo,
    const float* __restrict__ Wn1,  const float* __restrict__ Wn2,
    const float* __restrict__ We,   const float* __restrict__ Weo,
    const float* __restrict__ Wno,  const float* __restrict__ W1,
    const float* __restrict__ W2,   unsigned short* __restrict__ wT)
{
    const int bid = blockIdx.x;
    const int l = bid / 1088;
    int tl = bid % 1088;
    const float* src; int ld, K, Nn; unsigned short* dst;
    if (tl < 576) {
        int mid = tl >> 6; tl &= 63;
        K = 256; Nn = 256;
        if (mid < 3) {
            src = Wqkv + (size_t)l * 256 * 768 + mid * 256; ld = 768;
            dst = wT + (size_t)l * LAYER_W + (size_t)mid * 65536;
        } else {
            const float* bases[6] = {Wo, Wn1, Wn2, We, Weo, Wno};
            src = bases[mid - 3] + (size_t)l * 65536; ld = 256;
            dst = wT + (size_t)l * LAYER_W + OFF_WO + (size_t)(mid - 3) * 65536;
        }
    } else if (tl < 832) {
        tl -= 576; K = 256; Nn = 1024;
        src = W1 + (size_t)l * 262144; ld = 1024;
        dst = wT + (size_t)l * LAYER_W + OFF_W1;
    } else {
        tl -= 832; K = 1024; Nn = 256;
        src = W2 + (size_t)l * 262144; ld = 256;
        dst = wT + (size_t)l * LAYER_W + OFF_W2;
    }
    const int ntn = Nn >> 5;
    const int k0 = (tl / ntn) << 5, n0 = (tl % ntn) << 5;
    __shared__ float ts[32][33];
    const int t = threadIdx.x;
    const int kl = t >> 5, nl = t & 31;
    #pragma unroll
    for (int rr = 0; rr < 4; ++rr)
        ts[kl + rr * 8][nl] = src[(size_t)(k0 + kl + rr * 8) * ld + n0 + nl];
    __syncthreads();
    const int onl = t >> 3, okl = (t & 7) << 2;
    ushort4 o;
    o.x = f2bf(ts[okl + 0][onl]); o.y = f2bf(ts[okl + 1][onl]);
    o.z = f2bf(ts[okl + 2][onl]); o.w = f2bf(ts[okl + 3][onl]);
    *(ushort4*)&dst[(size_t)(n0 + onl) * K + k0 + okl] = o;
}

// ---------------- MFMA GEMM: C[M,N] = epi(A[M,K]_bf16 @ Bt[N,K]_bf16^T + bias) ----------------
// MODE 0: +bias ; MODE 1: gelu(+bias) ; MODE 2: res + ls*(+bias)
// bias2: if non-null, columns n>=256 take bias2[n-256] (fused dual-output GEMM)
template<int MODE, int OUTBF>
__global__ __launch_bounds__(256) void mgemm_kernel(
    const unsigned short* __restrict__ A, int lda,
    const unsigned short* __restrict__ Bt,
    const float* __restrict__ bias,
    const float* __restrict__ bias2,
    const float* __restrict__ res,
    const float* __restrict__ ls,
    void* __restrict__ Cv, int ldc, int K)
{
    __shared__ unsigned short As[64][72];
    __shared__ unsigned short Bs[64][72];
    const int m0 = blockIdx.y * 64, n0 = blockIdx.x * 64;
    const int t = threadIdx.x;
    const int l = t & 63, w = t >> 6;
    const int wr = (w >> 1) * 32, wc = (w & 1) * 32;
    const int srow = t >> 2, skc = (t & 3) * 16;
    const int frow = l & 15, kg = l >> 4;
    f32x4 acc[2][2];
    acc[0][0] = (f32x4){0.f,0.f,0.f,0.f}; acc[0][1] = acc[0][0];
    acc[1][0] = acc[0][0];                acc[1][1] = acc[0][0];
    for (int k0 = 0; k0 < K; k0 += 64) {
        const unsigned short* ap = A + (size_t)(m0 + srow) * lda + k0 + skc;
        uint4 aq0 = *(const uint4*)(ap);
        uint4 aq1 = *(const uint4*)(ap + 8);
        const unsigned short* bp = Bt + (size_t)(n0 + srow) * K + k0 + skc;
        uint4 bq0 = *(const uint4*)(bp);
        uint4 bq1 = *(const uint4*)(bp + 8);
        __syncthreads();
        *(uint4*)&As[srow][skc]     = aq0;
        *(uint4*)&As[srow][skc + 8] = aq1;
        *(uint4*)&Bs[srow][skc]     = bq0;
        *(uint4*)&Bs[srow][skc + 8] = bq1;
        __syncthreads();
        #pragma unroll
        for (int kk = 0; kk < 2; ++kk) {
            bf16x8 af0 = *(const bf16x8*)&As[wr + frow][kk * 32 + kg * 8];
            bf16x8 af1 = *(const bf16x8*)&As[wr + 16 + frow][kk * 32 + kg * 8];
            bf16x8 bf0 = *(const bf16x8*)&Bs[wc + frow][kk * 32 + kg * 8];
            bf16x8 bf1 = *(const bf16x8*)&Bs[wc + 16 + frow][kk * 32 + kg * 8];
            acc[0][0] = __builtin_amdgcn_mfma_f32_16x16x32_bf16(af0, bf0, acc[0][0], 0, 0, 0);
            acc[0][1] = __builtin_amdgcn_mfma_f32_16x16x32_bf16(af0, bf1, acc[0][1], 0, 0, 0);
            acc[1][0] = __builtin_amdgcn_mfma_f32_16x16x32_bf16(af1, bf0, acc[1][0], 0, 0, 0);
            acc[1][1] = __builtin_amdgcn_mfma_f32_16x16x32_bf16(af1, bf1, acc[1][1], 0, 0, 0);
        }
    }
    // C/D layout: col = lane&15, row = (lane>>4)*4 + reg
    #pragma unroll
    for (int fr = 0; fr < 2; ++fr) {
        #pragma unroll
        for (int fc = 0; fc < 2; ++fc) {
            int n = n0 + wc + fc * 16 + frow;
            float bv = (bias2 != nullptr && n >= 256) ? bias2[n - 256] : bias[n];
            float lv = (MODE == 2) ? ls[n] : 0.f;
            #pragma unroll
            for (int rg = 0; rg < 4; ++rg) {
                int m = m0 + wr + fr * 16 + kg * 4 + rg;
                float vv = acc[fr][fc][rg] + bv;
                if (MODE == 1) vv = gelu_f(vv);
                if (MODE == 2) vv = res[(size_t)m * ldc + n] + lv * vv;
                if (OUTBF) ((unsigned short*)Cv)[(size_t)m * ldc + n] = f2bf(vv);
                else       ((float*)Cv)[(size_t)m * ldc + n] = vv;
            }
        }
    }
}

// ---------------- MFMA flash attention ----------------
// 1152 blocks x 128 threads. Block = one (b,h) x 32 q-rows (2 waves x 16 rows).
// Mask staged via coalesced float4 -> bf16 LDS tile (double-buffered).
__global__ __launch_bounds__(128) void attn_kernel(
    const unsigned short* __restrict__ q, const unsigned short* __restrict__ kv,
    const float* __restrict__ mask, unsigned short* __restrict__ ctx)
{
    const int bid = blockIdx.x;
    const int h = bid & 7;
    const int qt = (bid >> 3) % 9;
    const int b = (bid >> 3) / 9;
    const int q0 = qt * 32;
    const int t = threadIdx.x;
    const int w = t >> 6, l = t & 63;
    const int lr = l & 15, lg = l >> 4;
    constexpr int NC = (HW_ + 63) / 64;   // 13

    __shared__ unsigned short Ks[2][64][40];
    __shared__ unsigned short Vs[2][32][72];
    __shared__ unsigned short Pl[2][16][72];
    __shared__ unsigned short Msk[2][32][68];   // total LDS = 32 KB exactly

    bf16x8 qfrag = *(const bf16x8*)(q + ((size_t)(b * NE_ + q0 + w * 16 + lr)) * D_ + h * DH_ + lg * 8);

    // staging assignment
    const int kkey = t >> 1, kdh = (t & 1) * 16;          // K: 1 key, 16 dh
    const int vdh = (t & 7) * 4, vk0 = (t >> 3) * 2;      // V: key pairs, 4 dh
    const int mrow = t >> 2, mcg = (t & 3) * 16;          // mask: row, 16-col group
    const unsigned short* kbase = kv + ((size_t)b * HW_) * 512 + h * DH_;
    const unsigned short* vbase = kv + ((size_t)b * HW_) * 512 + 256 + h * DH_;
    const float* mbase = mask + ((size_t)(b * H_ + h) * NE_ + q0 + mrow) * (size_t)HW_;

    uint4 kq0, kq1;
    ushort4 va[2], vb4[2];
    float mf[16];

    auto issue_kv = [&](int c0) {
        {
            int key = c0 + kkey;
            bool ok = key < HW_;
            const unsigned short* kp = kbase + (size_t)(ok ? key : 0) * 512 + kdh;
            kq0 = *(const uint4*)(kp);
            kq1 = *(const uint4*)(kp + 8);
            if (!ok) { kq0 = make_uint4(0,0,0,0); kq1 = kq0; }
        }
        #pragma unroll
        for (int r = 0; r < 2; ++r) {
            int key = c0 + vk0 + 32 * r;
            bool ok0 = key < HW_, ok1 = (key + 1) < HW_;
            const unsigned short* vp = vbase + (size_t)(ok0 ? key : 0) * 512 + vdh;
            va[r]  = *(const ushort4*)(vp);
            vb4[r] = *(const ushort4*)(vp + (ok1 ? 512 : 0));
            if (!ok0) va[r]  = make_ushort4(0,0,0,0);
            if (!ok1) vb4[r] = make_ushort4(0,0,0,0);
        }
    };
    auto issue_mask = [&](int c0) {
        if (c0 + 64 <= HW_) {
            #pragma unroll
            for (int i = 0; i < 4; ++i) {
                float4 m4 = *(const float4*)(mbase + c0 + mcg + i * 4);
                mf[i * 4 + 0] = m4.x; mf[i * 4 + 1] = m4.y;
                mf[i * 4 + 2] = m4.z; mf[i * 4 + 3] = m4.w;
            }
        } else {
            #pragma unroll
            for (int i = 0; i < 16; ++i) {
                int col = c0 + mcg + i;
                mf[i] = (col < HW_) ? mbase[col] : -1e30f;
            }
        }
    };
    auto write_kv = [&](int bufi) {
        *(uint4*)&Ks[bufi][kkey][kdh]     = kq0;
        *(uint4*)&Ks[bufi][kkey][kdh + 8] = kq1;
        #pragma unroll
        for (int r = 0; r < 2; ++r) {
            const unsigned short* a = (const unsigned short*)&va[r];
            const unsigned short* c = (const unsigned short*)&vb4[r];
            #pragma unroll
            for (int i = 0; i < 4; ++i)
                *(unsigned*)&Vs[bufi][vdh + i][vk0 + 32 * r] = (unsigned)a[i] | ((unsigned)c[i] << 16);
        }
    };
    auto write_mask = [&](int bufi) {
        uint4 p0 = make_uint4(pack2bf(mf[0], mf[1]),  pack2bf(mf[2], mf[3]),
                              pack2bf(mf[4], mf[5]),  pack2bf(mf[6], mf[7]));
        uint4 p1 = make_uint4(pack2bf(mf[8], mf[9]),  pack2bf(mf[10], mf[11]),
                              pack2bf(mf[12], mf[13]), pack2bf(mf[14], mf[15]));
        *(uint4*)&Msk[bufi][mrow][mcg]     = p0;
        *(uint4*)&Msk[bufi][mrow][mcg + 8] = p1;
    };

    f32x4 oacc[2];
    oacc[0] = (f32x4){0.f, 0.f, 0.f, 0.f}; oacc[1] = oacc[0];
    float m_i[4] = {-INFINITY, -INFINITY, -INFINITY, -INFINITY};
    float l_i[4] = {0.f, 0.f, 0.f, 0.f};

    issue_kv(0);
    issue_mask(0);
    write_kv(0);
    write_mask(0);
    __syncthreads();

    for (int c = 0; c < NC; ++c) {
        const int c0 = c * 64;
        const int cb = c & 1, nb = cb ^ 1;
        if (c + 1 < NC) { issue_kv(c0 + 64); issue_mask(c0 + 64); }

        // QK^T: S[16 q, 64 keys]
        f32x4 sacc[4];
        #pragma unroll
        for (int fc = 0; fc < 4; ++fc) {
            sacc[fc] = (f32x4){0.f, 0.f, 0.f, 0.f};
            bf16x8 kf = *(const bf16x8*)&Ks[cb][fc * 16 + lr][lg * 8];
            sacc[fc] = __builtin_amdgcn_mfma_f32_16x16x32_bf16(qfrag, kf, sacc[fc], 0, 0, 0);
        }
        float s[4][4];   // [fc][reg]
        #pragma unroll
        for (int fc = 0; fc < 4; ++fc)
            #pragma unroll
            for (int rg = 0; rg < 4; ++rg)
                s[fc][rg] = sacc[fc][rg] * SCALE_ + bf2f(Msk[cb][w * 16 + lg * 4 + rg][fc * 16 + lr]);

        // online softmax (rows = lg*4+rg, reduce across 16-lane group)
        float mloc[4];
        #pragma unroll
        for (int rg = 0; rg < 4; ++rg)
            mloc[rg] = fmaxf(fmaxf(s[0][rg], s[1][rg]), fmaxf(s[2][rg], s[3][rg]));
        #pragma unroll
        for (int off = 1; off < 16; off <<= 1)
            #pragma unroll
            for (int rg = 0; rg < 4; ++rg)
                mloc[rg] = fmaxf(mloc[rg], __shfl_xor(mloc[rg], off));
        float scl[4], lloc[4];
        #pragma unroll
        for (int rg = 0; rg < 4; ++rg) {
            float mn = fmaxf(m_i[rg], mloc[rg]);
            scl[rg] = __expf(m_i[rg] - mn);
            m_i[rg] = mn;
        }
        #pragma unroll
        for (int rg = 0; rg < 4; ++rg) {
            float acc = 0.f;
            #pragma unroll
            for (int fc = 0; fc < 4; ++fc) {
                float p = __expf(s[fc][rg] - m_i[rg]);
                s[fc][rg] = p;
                acc += p;
            }
            lloc[rg] = acc;
        }
        #pragma unroll
        for (int off = 1; off < 16; off <<= 1)
            #pragma unroll
            for (int rg = 0; rg < 4; ++rg)
                lloc[rg] += __shfl_xor(lloc[rg], off);
        #pragma unroll
        for (int rg = 0; rg < 4; ++rg) {
            l_i[rg] = l_i[rg] * scl[rg] + lloc[rg];
            oacc[0][rg] *= scl[rg];
            oacc[1][rg] *= scl[rg];
        }

        // P -> LDS (wave-private), then PV
        #pragma unroll
        for (int fc = 0; fc < 4; ++fc)
            #pragma unroll
            for (int rg = 0; rg < 4; ++rg)
                Pl[w][lg * 4 + rg][fc * 16 + lr] = f2bf(s[fc][rg]);
        #pragma unroll
        for (int ks2 = 0; ks2 < 2; ++ks2) {
            bf16x8 pf = *(const bf16x8*)&Pl[w][lr][ks2 * 32 + lg * 8];
            #pragma unroll
            for (int d2 = 0; d2 < 2; ++d2) {
                bf16x8 vf = *(const bf16x8*)&Vs[cb][d2 * 16 + lr][ks2 * 32 + lg * 8];
                oacc[d2] = __builtin_amdgcn_mfma_f32_16x16x32_bf16(pf, vf, oacc[d2], 0, 0, 0);
            }
        }

        if (c + 1 < NC) {
            write_kv(nb);
            write_mask(nb);
            __syncthreads();
        }
    }

    unsigned short* cbase = ctx + ((size_t)(b * NE_ + q0 + w * 16 + lg * 4)) * D_ + h * DH_;
    #pragma unroll
    for (int rg = 0; rg < 4; ++rg) {
        float inv = 1.0f / l_i[rg];
        #pragma unroll
        for (int d2 = 0; d2 < 2; ++d2)
            cbase[(size_t)rg * D_ + d2 * 16 + lr] = f2bf(oacc[d2][rg] * inv);
    }
}

// ---------------- GAT kernels ----------------

// hid holds ep (bf16) on entry; gn12 [BN][512] = (gn1 | gn2)
__global__ __launch_bounds__(256) void hidden_kernel(
    const float* __restrict__ gn12,
    unsigned short* __restrict__ hid, const int* __restrict__ idx0,
    const float* __restrict__ attn_p_l, float* __restrict__ pres) {
    int e = blockIdx.x;
    int d = threadIdx.x;
    int n = idx0[e];
    float x = bf2f(hid[(size_t)e * D_ + d]) + gn12[(size_t)n * 512 + d] + gn12[(size_t)n * 512 + 256 + d];
    float hv = gelu_f(x);
    hid[(size_t)e * D_ + d] = f2bf(hv);
    float pr = hv * attn_p_l[d];
    #pragma unroll
    for (int o = 1; o < 32; o <<= 1) pr += __shfl_xor(pr, o);
    if ((d & 31) == 0) pres[e * H_ + (d >> 5)] = pr;
}

__global__ void segsoft_kernel(const float* __restrict__ pres, const int* __restrict__ csr_off,
                               const int* __restrict__ csr_perm,
                               float* __restrict__ mseg, float* __restrict__ denom) {
    int tid = blockIdx.x * 256 + threadIdx.x;   // BN*H
    int n = tid >> 3, h = tid & 7;
    int s = csr_off[n], e2 = csr_off[n + 1];
    float mx = -INFINITY;
    for (int i = s; i < e2; ++i) mx = fmaxf(mx, pres[csr_perm[i] * H_ + h]);
    float sum = 0.f;
    for (int i = s; i < e2; ++i) sum += expf(pres[csr_perm[i] * H_ + h] - mx);
    mseg[tid] = mx;
    denom[tid] = sum;
}

__global__ void vin_kernel(const unsigned short* __restrict__ nodes_f,
                           const float* __restrict__ new_edges,
                           const int* __restrict__ idx1, unsigned short* __restrict__ vin) {
    int tid = blockIdx.x * 256 + threadIdx.x;   // BE*D
    int e = tid >> 8, d = tid & 255;
    vin[tid] = f2bf(bf2f(nodes_f[(size_t)idx1[e] * D_ + d]) + new_edges[tid]);
}

// nodeagg with inline alpha = exp(pres - mseg)/denom
__global__ __launch_bounds__(256) void nodeagg_kernel(
    const float* __restrict__ vals, const float* __restrict__ pres,
    const float* __restrict__ mseg, const float* __restrict__ denom,
    const int* __restrict__ csr_off, const int* __restrict__ csr_perm,
    float* __restrict__ new_nodes) {
    int n = blockIdx.x;
    int d = threadIdx.x;
    int s = csr_off[n], e2 = csr_off[n + 1];
    int h = d >> 5;
    float ms = mseg[n * H_ + h];
    float rd = 1.0f / denom[n * H_ + h];
    float acc = 0.f;
    for (int i = s; i < e2; ++i) {
        int e = csr_perm[i];
        float a = expf(pres[e * H_ + h] - ms) * rd;
        acc += vals[(size_t)e * D_ + d] * a;
    }
    new_nodes[(size_t)n * D_ + d] = acc;
}

// ---------------- CSR build (deterministic) ----------------

__global__ void zero_counts(int* counts) {
    int t = blockIdx.x * 256 + threadIdx.x;
    if (t < BN_) counts[t] = 0;
}

__global__ void csr_count(const int* __restrict__ idx0, int* __restrict__ counts) {
    int e = blockIdx.x * 256 + threadIdx.x;
    if (e < BE_) atomicAdd(&counts[idx0[e]], 1);
}

__global__ __launch_bounds__(512) void csr_scan(const int* __restrict__ counts, int* __restrict__ csr_off) {
    __shared__ int buf[BN_];
    int t = threadIdx.x;
    int c = counts[t];
    buf[t] = c;
    __syncthreads();
    for (int o = 1; o < BN_; o <<= 1) {
        int add = (t >= o) ? buf[t - o] : 0;
        __syncthreads();
        buf[t] += add;
        __syncthreads();
    }
    csr_off[t] = buf[t] - c;
    if (t == BN_ - 1) csr_off[BN_] = buf[t];
}

__global__ __launch_bounds__(64) void csr_fill(const int* __restrict__ idx0,
                                               const int* __restrict__ csr_off,
                                               int* __restrict__ csr_perm) {
    int n = blockIdx.x;
    int lane = threadIdx.x;
    int w = csr_off[n];
    for (int c0 = 0; c0 < BE_; c0 += 64) {
        int e = c0 + lane;
        bool m = (idx0[e] == n);
        unsigned long long bal = __ballot(m);
        if (m) {
            int pre = __popcll(bal & ((1ull << lane) - 1ull));
            csr_perm[w + pre] = e;
        }
        w += __popcll(bal);
    }
}

// ---------------- host orchestration ----------------

static void launch_mgemm(hipStream_t s, int mode, int outbf,
                         const unsigned short* A, int lda, const unsigned short* Bt,
                         const float* bias, const float* bias2, const float* res, const float* ls,
                         void* C, int ldc, int M, int N, int K) {
    dim3 g(N / 64, M / 64);
    if (mode == 0) {
        if (outbf) mgemm_kernel<0,1><<<g, 256, 0, s>>>(A, lda, Bt, bias, bias2, res, ls, C, ldc, K);
        else       mgemm_kernel<0,0><<<g, 256, 0, s>>>(A, lda, Bt, bias, bias2, res, ls, C, ldc, K);
    } else if (mode == 1) {
        mgemm_kernel<1,1><<<g, 256, 0, s>>>(A, lda, Bt, bias, bias2, res, ls, C, ldc, K);
    } else {
        mgemm_kernel<2,0><<<g, 256, 0, s>>>(A, lda, Bt, bias, bias2, res, ls, C, ldc, K);
    }
}

extern "C" void kernel_launch(void* const* d_in, const int* in_sizes, int n_in,
                              void* d_out, int out_size, void* d_ws, size_t ws_size,
                              hipStream_t stream) {
    const float* nodes    = (const float*)d_in[0];
    const float* edges    = (const float*)d_in[1];
    const float* images   = (const float*)d_in[2];
    const float* mask     = (const float*)d_in[3];
    const float* node_enc = (const float*)d_in[4];
    const float* edge_enc = (const float*)d_in[5];
    const float* ln1_g = (const float*)d_in[6];
    const float* ln1_b = (const float*)d_in[7];
    const float* Wqkv  = (const float*)d_in[8];
    const float* bqkv  = (const float*)d_in[9];
    const float* Wo    = (const float*)d_in[10];
    const float* bo    = (const float*)d_in[11];
    const float* ls1   = (const float*)d_in[12];
    const float* ln2_g = (const float*)d_in[13];
    const float* ln2_b = (const float*)d_in[14];
    const float* Wn1   = (const float*)d_in[15];
    const float* bn1   = (const float*)d_in[16];
    const float* Wn2   = (const float*)d_in[17];
    const float* bn2   = (const float*)d_in[18];
    const float* We    = (const float*)d_in[19];
    const float* be    = (const float*)d_in[20];
    const float* attn_p= (const float*)d_in[21];
    const float* Weo   = (const float*)d_in[22];
    const float* beo   = (const float*)d_in[23];
    const float* Wno   = (const float*)d_in[24];
    const float* bno   = (const float*)d_in[25];
    const float* ls2   = (const float*)d_in[26];
    const float* ln3_g = (const float*)d_in[27];
    const float* ln3_b = (const float*)d_in[28];
    const float* W1    = (const float*)d_in[29];
    const float* b1    = (const float*)d_in[30];
    const float* W2    = (const float*)d_in[31];
    const float* b2    = (const float*)d_in[32];
    const float* ls3   = (const float*)d_in[33];
    const int*   edge_index = (const int*)d_in[34];
    const int* idx0 = edge_index;
    const int* idx1 = edge_index + BE_;

    float* ne = (float*)d_out;   // d_out doubles as the running `ne` buffer

    float* cur = (float*)d_ws;
    auto alloc = [&](size_t nfl) { float* p = cur; cur += nfl; return p; };
    auto allocbf = [&](size_t nbf) { float* p = cur; cur += (nbf + 1) / 2; return (unsigned short*)p; };

    unsigned short* lnbuf   = allocbf((size_t)B_ * NE_ * D_);
    unsigned short* qb      = allocbf((size_t)B_ * NE_ * D_);
    unsigned short* kvb     = allocbf((size_t)B_ * HW_ * 512);     // K|V fused, ld=512
    unsigned short* ffnh    = kvb;   // alias: kv dead by FFN time (needs 4.7M of 6.4M halves)
    unsigned short* imgbf   = allocbf((size_t)B_ * HW_ * D_);
    unsigned short* ctxb    = allocbf((size_t)B_ * NE_ * D_);
    unsigned short* nodes_f = allocbf((size_t)BN_ * D_);
    unsigned short* edges_f = allocbf((size_t)BE_ * D_);
    unsigned short* hid     = allocbf((size_t)BE_ * D_);
    unsigned short* vin     = allocbf((size_t)BE_ * D_);
    float* gn12     = alloc((size_t)BN_ * 512);
    float* pres     = alloc((size_t)BE_ * H_);
    float* mseg     = alloc((size_t)BN_ * H_);
    float* denom    = alloc((size_t)BN_ * H_);
    float* new_edges= alloc((size_t)BE_ * D_);
    float* valsb    = alloc((size_t)BE_ * D_);
    float* new_nodes= alloc((size_t)BN_ * D_);
    int* counts   = (int*)cur; cur += BN_;
    int* csr_off  = (int*)cur; cur += BN_ + 4;
    int* csr_perm = (int*)cur; cur += BE_;
    cur = (float*)(((uintptr_t)cur + 255) & ~(uintptr_t)255);
    unsigned short* wT = (unsigned short*)cur;   // 4 * LAYER_W bf16

    // ---- once-per-call preprocessing ----
    wtrans_kernel<<<4 * 1088, 256, 0, stream>>>(Wqkv, Wo, Wn1, Wn2, We, Weo, Wno, W1, W2, wT);
    imgcast_kernel<<<(B_ * HW_ * D_) / (256 * 8), 256, 0, stream>>>(images, imgbf);
    zero_counts<<<2, 256, 0, stream>>>(counts);
    csr_count<<<BE_ / 256, 256, 0, stream>>>(idx0, counts);
    csr_scan<<<1, 512, 0, stream>>>(counts, csr_off);
    csr_fill<<<BN_, 64, 0, stream>>>(idx0, csr_off, csr_perm);
    concat_kernel<<<(B_ * NE_ * D_) / 256, 256, 0, stream>>>(nodes, edges, ne);

    for (int l = 0; l < L_; ++l) {
        const unsigned short* wTl = wT + (size_t)l * LAYER_W;
        const float* bqkv_l = bqkv + (size_t)l * 3 * D_;

        // ---- cross attention ----
        ln_kernel<<<B_ * NE_, 256, 0, stream>>>(ne, lnbuf, ln1_g + l * D_, ln1_b + l * D_);
        launch_mgemm(stream, 0, 1, lnbuf, D_, wTl + OFF_Q, bqkv_l, nullptr, nullptr, nullptr,
                     qb, D_, B_ * NE_, D_, D_);
        launch_mgemm(stream, 0, 1, imgbf, D_, wTl + OFF_K, bqkv_l + D_, nullptr, nullptr, nullptr,
                     kvb, 512, B_ * HW_, 512, D_);
        attn_kernel<<<1152, 128, 0, stream>>>(qb, kvb, mask, ctxb);
        launch_mgemm(stream, 2, 0, ctxb, D_, wTl + OFF_WO, bo + l * D_, nullptr, ne, ls1 + l * D_,
                     ne, D_, B_ * NE_, D_, D_);

        // ---- GAT ----
        ln2enc_kernel<<<B_ * NE_, 256, 0, stream>>>(ne, ln2_g + l * D_, ln2_b + l * D_,
                                                    node_enc, edge_enc, nodes_f, edges_f);
        launch_mgemm(stream, 0, 0, nodes_f, D_, wTl + OFF_WN1, bn1 + l * D_, bn2 + l * D_,
                     nullptr, nullptr, gn12, 512, BN_, 512, D_);
        launch_mgemm(stream, 0, 1, edges_f, D_, wTl + OFF_WE, be + l * D_, nullptr, nullptr, nullptr,
                     hid, D_, BE_, D_, D_);
        hidden_kernel<<<BE_, 256, 0, stream>>>(gn12, hid, idx0, attn_p + (size_t)l * H_ * DH_, pres);
        segsoft_kernel<<<(BN_ * H_) / 256, 256, 0, stream>>>(pres, csr_off, csr_perm, mseg, denom);
        launch_mgemm(stream, 0, 0, hid, D_, wTl + OFF_WEO, beo + l * D_, nullptr, nullptr, nullptr,
                     new_edges, D_, BE_, D_, D_);
        vin_kernel<<<(BE_ * D_) / 256, 256, 0, stream>>>(nodes_f, new_edges, idx1, vin);
        launch_mgemm(stream, 0, 0, vin, D_, wTl + OFF_WNO, bno + l * D_, nullptr, nullptr, nullptr,
                     valsb, D_, BE_, D_, D_);
        nodeagg_kernel<<<BN_, 256, 0, stream>>>(valsb, pres, mseg, denom, csr_off, csr_perm, new_nodes);
        gatres_ln_kernel<<<B_ * NE_, 256, 0, stream>>>(ne, new_nodes, new_edges, ls2 + l * D_,
                                                       ln3_g + l * D_, ln3_b + l * D_, lnbuf);

        // ---- FFN ----
        launch_mgemm(stream, 1, 1, lnbuf, D_, wTl + OFF_W1, b1 + l * FF_, nullptr, nullptr, nullptr,
                     ffnh, FF_, B_ * NE_, FF_, D_);
        launch_mgemm(stream, 2, 0, ffnh, FF_, wTl + OFF_W2, b2 + l * D_, nullptr, ne, ls3 + l * D_,
                     ne, D_, B_ * NE_, D_, FF_);
    }
}